// Round 1
// baseline (4177.660 us; speedup 1.0000x reference)
//
#include <hip/hip_runtime.h>
#include <cstddef>

#define N_NODES 20000
#define N_EDGES 320000
#define E_TOT   (N_EDGES + N_NODES)   // 340000
#define HEADS   16

// ---------------------------------------------------------------------------
// Layer 1: x[N,3] @ W[3,1024] -> h[N,1024]
__global__ __launch_bounds__(256)
void k_lin1(const float* __restrict__ x, const float* __restrict__ W,
            float* __restrict__ h) {
    int idx = blockIdx.x * 256 + threadIdx.x;
    if (idx >= N_NODES * 1024) return;
    int n = idx >> 10, j = idx & 1023;
    float v = x[n*3+0]*W[j] + x[n*3+1]*W[1024+j] + x[n*3+2]*W[2048+j];
    h[idx] = v;
}

// ---------------------------------------------------------------------------
// Tiled fp32 GEMM: C[N,M] = A[N,K] * B[K,M].  BM=BN=128, BK=16, 256 thr, 8x8.
#define BM 128
#define BN 128
#define BK 16
__global__ __launch_bounds__(256)
void k_gemm(const float* __restrict__ A, const float* __restrict__ B,
            float* __restrict__ C, int N, int K, int M) {
    __shared__ float As[BK][BM + 4];
    __shared__ float Bs[BK][BN + 4];
    const int row0 = blockIdx.x * BM;
    const int col0 = blockIdx.y * BN;
    const int tid = threadIdx.x;
    const int tx = tid & 15, ty = tid >> 4;

    float acc[8][8];
#pragma unroll
    for (int i = 0; i < 8; ++i)
#pragma unroll
        for (int j = 0; j < 8; ++j) acc[i][j] = 0.f;

    for (int k0 = 0; k0 < K; k0 += BK) {
        // load A tile (transpose into LDS)
#pragma unroll
        for (int half = 0; half < 2; ++half) {
            int r  = (tid >> 2) + half * 64;
            int kk = (tid & 3) * 4;
            int gr = row0 + r; if (gr >= N) gr = N - 1;
            float4 av = *reinterpret_cast<const float4*>(&A[(size_t)gr * K + k0 + kk]);
            As[kk+0][r] = av.x; As[kk+1][r] = av.y;
            As[kk+2][r] = av.z; As[kk+3][r] = av.w;
        }
        // load B tile
#pragma unroll
        for (int half = 0; half < 2; ++half) {
            int kr = (tid >> 5) + half * 8;
            int c4 = (tid & 31) * 4;
            float4 bv = *reinterpret_cast<const float4*>(&B[(size_t)(k0 + kr) * M + col0 + c4]);
            *reinterpret_cast<float4*>(&Bs[kr][c4]) = bv;
        }
        __syncthreads();
#pragma unroll
        for (int k = 0; k < BK; ++k) {
            float a[8], b[8];
            *reinterpret_cast<float4*>(&a[0]) = *reinterpret_cast<const float4*>(&As[k][ty*8]);
            *reinterpret_cast<float4*>(&a[4]) = *reinterpret_cast<const float4*>(&As[k][ty*8+4]);
            *reinterpret_cast<float4*>(&b[0]) = *reinterpret_cast<const float4*>(&Bs[k][tx*8]);
            *reinterpret_cast<float4*>(&b[4]) = *reinterpret_cast<const float4*>(&Bs[k][tx*8+4]);
#pragma unroll
            for (int i = 0; i < 8; ++i)
#pragma unroll
                for (int j = 0; j < 8; ++j) acc[i][j] = fmaf(a[i], b[j], acc[i][j]);
        }
        __syncthreads();
    }
#pragma unroll
    for (int i = 0; i < 8; ++i) {
        int gr = row0 + ty*8 + i;
        if (gr < N) {
#pragma unroll
            for (int j = 0; j < 8; ++j)
                C[(size_t)gr * M + col0 + tx*8 + j] = acc[i][j];
        }
    }
}

// ---------------------------------------------------------------------------
// alpha_s/alpha_d: one 64-lane wave per (node, head)
__global__ __launch_bounds__(256)
void k_alpha(const float* __restrict__ h, const float* __restrict__ a_s,
             const float* __restrict__ a_d, float* __restrict__ as_out,
             float* __restrict__ ad_out, int C, int M) {
    int pair = blockIdx.x * 4 + (threadIdx.x >> 6);
    int lane = threadIdx.x & 63;
    if (pair >= N_NODES * HEADS) return;
    int n = pair >> 4, hd = pair & 15;
    float vs = 0.f, vd = 0.f;
    if (lane < C) {
        float hv = h[(size_t)n * M + hd * C + lane];
        vs = hv * a_s[hd * C + lane];
        vd = hv * a_d[hd * C + lane];
    }
#pragma unroll
    for (int off = 32; off > 0; off >>= 1) {
        vs += __shfl_down(vs, off);
        vd += __shfl_down(vd, off);
    }
    if (lane == 0) { as_out[pair] = vs; ad_out[pair] = vd; }
}

// ---------------------------------------------------------------------------
// per-edge pre-softmax logits (leaky relu)
__global__ __launch_bounds__(256)
void k_edge(const int* __restrict__ ei, const float* __restrict__ as_,
            const float* __restrict__ ad_, float* __restrict__ ev) {
    int t = blockIdx.x * 256 + threadIdx.x;
    if (t >= E_TOT * HEADS) return;
    int e = t >> 4, hd = t & 15;
    int s, d;
    if (e < N_EDGES) { s = ei[e]; d = ei[N_EDGES + e]; }
    else             { s = d = e - N_EDGES; }
    float v = as_[s * 16 + hd] + ad_[d * 16 + hd];
    ev[t] = v > 0.f ? v : 0.2f * v;
}

// ---------------------------------------------------------------------------
// CSR build
__global__ void k_zero_i(int* __restrict__ p, int n) {
    int t = blockIdx.x * 256 + threadIdx.x;
    if (t < n) p[t] = 0;
}
__global__ void k_hist(const int* __restrict__ ei, int* __restrict__ deg) {
    int e = blockIdx.x * 256 + threadIdx.x;
    if (e >= E_TOT) return;
    int d = (e < N_EDGES) ? ei[N_EDGES + e] : e - N_EDGES;
    atomicAdd(&deg[d], 1);
}
__global__ __launch_bounds__(256)
void k_scan(const int* __restrict__ deg, int* __restrict__ rowstart,
            int* __restrict__ cursor) {
    __shared__ int sh[256];
    int carry = 0;
    for (int base = 0; base < N_NODES; base += 256) {
        int i = base + threadIdx.x;
        int v = (i < N_NODES) ? deg[i] : 0;
        sh[threadIdx.x] = v;
        __syncthreads();
        for (int off = 1; off < 256; off <<= 1) {
            int t = (threadIdx.x >= off) ? sh[threadIdx.x - off] : 0;
            __syncthreads();
            sh[threadIdx.x] += t;
            __syncthreads();
        }
        if (i < N_NODES) {
            int excl = carry + sh[threadIdx.x] - v;
            rowstart[i] = excl;
            cursor[i] = excl;
        }
        carry += sh[255];
        __syncthreads();
    }
    if (threadIdx.x == 0) rowstart[N_NODES] = carry;
}
__global__ void k_scatter(const int* __restrict__ ei, int* __restrict__ cursor,
                          int* __restrict__ csr_src, int* __restrict__ csr_eid) {
    int e = blockIdx.x * 256 + threadIdx.x;
    if (e >= E_TOT) return;
    int s, d;
    if (e < N_EDGES) { s = ei[e]; d = ei[N_EDGES + e]; }
    else             { s = d = e - N_EDGES; }
    int slot = atomicAdd(&cursor[d], 1);
    csr_src[slot] = s;
    csr_eid[slot] = e;
}

// ---------------------------------------------------------------------------
// segment softmax per (node, head), in place on ev
__global__ __launch_bounds__(256)
void k_softmax(const int* __restrict__ rowstart, const int* __restrict__ csr_eid,
               float* __restrict__ ev) {
    int t = blockIdx.x * 256 + threadIdx.x;
    if (t >= N_NODES * HEADS) return;
    int n = t >> 4, hd = t & 15;
    int s0 = rowstart[n], s1 = rowstart[n + 1];
    float m = -1e30f;
    for (int j = s0; j < s1; ++j) m = fmaxf(m, ev[csr_eid[j] * 16 + hd]);
    float den = 0.f;
    for (int j = s0; j < s1; ++j) den += __expf(ev[csr_eid[j] * 16 + hd] - m);
    float inv = 1.f / (den + 1e-16f);
    for (int j = s0; j < s1; ++j) {
        int idx = csr_eid[j] * 16 + hd;
        ev[idx] = __expf(ev[idx] - m) * inv;
    }
}

// ---------------------------------------------------------------------------
// aggregation: out[n,f] = sum_edges alpha[e, f/C] * h[src, f]  (+bias, relu)
// vectorized path for M=1024 (thread owns f = t*4..t*4+3)
template<bool RELU>
__global__ __launch_bounds__(256)
void k_agg1024(const float* __restrict__ h, const float* __restrict__ alpha,
               const int* __restrict__ rowstart, const int* __restrict__ csr_src,
               const int* __restrict__ csr_eid, const float* __restrict__ bias,
               float* __restrict__ out) {
    int n = blockIdx.x;
    int s0 = rowstart[n], s1 = rowstart[n + 1];
    int t = threadIdx.x;
    int f0 = t * 4;
    int hd = f0 >> 6;                 // C=64, wave-uniform
    float4 acc = {0.f, 0.f, 0.f, 0.f};
    for (int j = s0; j < s1; ++j) {
        int src = csr_src[j];
        int eid = csr_eid[j];
        float a = alpha[(size_t)eid * 16 + hd];
        float4 hv = *reinterpret_cast<const float4*>(&h[(size_t)src * 1024 + f0]);
        acc.x = fmaf(a, hv.x, acc.x);
        acc.y = fmaf(a, hv.y, acc.y);
        acc.z = fmaf(a, hv.z, acc.z);
        acc.w = fmaf(a, hv.w, acc.w);
    }
    float4 bv = *reinterpret_cast<const float4*>(&bias[f0]);
    acc.x += bv.x; acc.y += bv.y; acc.z += bv.z; acc.w += bv.w;
    if (RELU) {
        acc.x = fmaxf(acc.x, 0.f); acc.y = fmaxf(acc.y, 0.f);
        acc.z = fmaxf(acc.z, 0.f); acc.w = fmaxf(acc.w, 0.f);
    }
    *reinterpret_cast<float4*>(&out[(size_t)n * 1024 + f0]) = acc;
}

// scalar path for M=768 (C=48), thread owns f = t, t+256, t+512
__global__ __launch_bounds__(256)
void k_agg768(const float* __restrict__ h, const float* __restrict__ alpha,
              const int* __restrict__ rowstart, const int* __restrict__ csr_src,
              const int* __restrict__ csr_eid, const float* __restrict__ bias,
              float* __restrict__ out) {
    int n = blockIdx.x;
    int s0 = rowstart[n], s1 = rowstart[n + 1];
    int t = threadIdx.x;
    float acc[3] = {0.f, 0.f, 0.f};
    int hd[3];
#pragma unroll
    for (int i = 0; i < 3; ++i) hd[i] = (t + i * 256) / 48;
    for (int j = s0; j < s1; ++j) {
        int src = csr_src[j];
        int eid = csr_eid[j];
        const float* hrow = h + (size_t)src * 768;
        const float* al = alpha + (size_t)eid * 16;
#pragma unroll
        for (int i = 0; i < 3; ++i)
            acc[i] = fmaf(al[hd[i]], hrow[t + i * 256], acc[i]);
    }
#pragma unroll
    for (int i = 0; i < 3; ++i) {
        int f = t + i * 256;
        float v = acc[i] + bias[f];
        out[(size_t)n * 768 + f] = v;   // last layer: no relu
    }
}

// ---------------------------------------------------------------------------
// final: out[1,768] = sum_n x[n, :]
__global__ __launch_bounds__(256)
void k_colsum(const float* __restrict__ x, float* __restrict__ out) {
    int f = blockIdx.x * 256 + threadIdx.x;   // blockIdx.x in [0,3)
    int chunk = blockIdx.y;                   // [0,32)
    int n0 = chunk * 625, n1 = n0 + 625;
    float s = 0.f;
    for (int n = n0; n < n1; ++n) s += x[(size_t)n * 768 + f];
    atomicAdd(&out[f], s);
}

// ---------------------------------------------------------------------------
extern "C" void kernel_launch(void* const* d_in, const int* in_sizes, int n_in,
                              void* d_out, int out_size, void* d_ws, size_t ws_size,
                              hipStream_t stream) {
    const float* x0 = (const float*)d_in[0];
    const int*   ei = (const int*)d_in[1];

    // workspace carve (floats)
    float* fws = (float*)d_ws;
    size_t o = 0;
    float* xA = fws + o; o += (size_t)N_NODES * 1024;
    float* xB = fws + o; o += (size_t)N_NODES * 1024;
    float* as_ = fws + o; o += (size_t)N_NODES * HEADS;
    float* ad_ = fws + o; o += (size_t)N_NODES * HEADS;
    float* ev  = fws + o; o += (size_t)E_TOT * HEADS;
    int* deg      = (int*)(fws + o); o += N_NODES;
    int* rowstart = (int*)(fws + o); o += N_NODES + 1;
    int* cursor   = (int*)(fws + o); o += N_NODES;
    int* csr_src  = (int*)(fws + o); o += E_TOT;
    int* csr_eid  = (int*)(fws + o); o += E_TOT;

    // ---- CSR build (once; same for all layers) ----
    k_zero_i<<<(N_NODES + 255) / 256, 256, 0, stream>>>(deg, N_NODES);
    k_hist<<<(E_TOT + 255) / 256, 256, 0, stream>>>(ei, deg);
    k_scan<<<1, 256, 0, stream>>>(deg, rowstart, cursor);
    k_scatter<<<(E_TOT + 255) / 256, 256, 0, stream>>>(ei, cursor, csr_src, csr_eid);

    // ---- layers ----
    // layer params at d_in[2 + 4*l + {0:W, 1:a_s, 2:a_d, 3:b}]
    for (int l = 0; l < 6; ++l) {
        const float* W  = (const float*)d_in[2 + 4 * l + 0];
        const float* asv = (const float*)d_in[2 + 4 * l + 1];
        const float* adv = (const float*)d_in[2 + 4 * l + 2];
        const float* bv  = (const float*)d_in[2 + 4 * l + 3];
        int C = (l == 5) ? 48 : 64;
        int M = HEADS * C;          // 1024 or 768

        // h = x @ W  -> xB
        if (l == 0) {
            k_lin1<<<(N_NODES * 1024 + 255) / 256, 256, 0, stream>>>(x0, W, xB);
        } else {
            dim3 grid((N_NODES + BM - 1) / BM, M / BN);
            k_gemm<<<grid, 256, 0, stream>>>(xA, W, xB, N_NODES, 1024, M);
        }
        // alpha_s / alpha_d
        k_alpha<<<(N_NODES * HEADS + 3) / 4, 256, 0, stream>>>(xB, asv, adv, as_, ad_, C, M);
        // edge logits
        k_edge<<<(E_TOT * HEADS + 255) / 256, 256, 0, stream>>>(ei, as_, ad_, ev);
        // segment softmax
        k_softmax<<<(N_NODES * HEADS + 255) / 256, 256, 0, stream>>>(rowstart, csr_eid, ev);
        // aggregation (+bias, +relu except last) -> xA
        if (M == 1024) {
            k_agg1024<true><<<N_NODES, 256, 0, stream>>>(xB, ev, rowstart, csr_src, csr_eid, bv, xA);
        } else {
            k_agg768<<<N_NODES, 256, 0, stream>>>(xB, ev, rowstart, csr_src, csr_eid, bv, xA);
        }
    }

    // final column sum -> d_out
    hipMemsetAsync(d_out, 0, (size_t)out_size * sizeof(float), stream);
    dim3 cgrid(3, 32);
    k_colsum<<<cgrid, 256, 0, stream>>>(xA, (float*)d_out);
}

// Round 2
// 2715.102 us; speedup vs baseline: 1.5387x; 1.5387x over previous
//
#include <hip/hip_runtime.h>
#include <cstddef>
#include <cstdint>

#define N_NODES 20000
#define N_EDGES 320000
#define E_TOT   (N_EDGES + N_NODES)   // 340000
#define HEADS   16

typedef __bf16 bf16;
typedef __attribute__((ext_vector_type(8))) __bf16 bf16x8;
typedef __attribute__((ext_vector_type(4))) __bf16 bf16x4;
typedef __attribute__((ext_vector_type(4))) float  f32x4;

__device__ __forceinline__ void gll16(const void* g, void* l) {
    __builtin_amdgcn_global_load_lds(
        (const __attribute__((address_space(1))) unsigned int*)g,
        (__attribute__((address_space(3))) unsigned int*)l, 16, 0, 0);
}

// ---------------------------------------------------------------------------
// Layer 1: x[N,3] @ W[3,1024] -> h[N,1024]  (fp32 vector, K=3 trivial)
__global__ __launch_bounds__(256)
void k_lin1(const float* __restrict__ x, const float* __restrict__ W,
            float* __restrict__ h) {
    int idx = blockIdx.x * 256 + threadIdx.x;
    if (idx >= N_NODES * 1024) return;
    int n = idx >> 10, j = idx & 1023;
    float v = x[n*3+0]*W[j] + x[n*3+1]*W[1024+j] + x[n*3+2]*W[2048+j];
    h[idx] = v;
}

// ---------------------------------------------------------------------------
// W [1024][M] fp32 -> Wt_hi/Wt_lo [M][1024] bf16 (transpose + hi/lo split)
__global__ __launch_bounds__(256)
void k_convW(const float* __restrict__ W, bf16* __restrict__ Th,
             bf16* __restrict__ Tl, int M) {
    __shared__ float t[32][33];
    int m0 = blockIdx.x * 32, k0 = blockIdx.y * 32;
    int j = threadIdx.x & 31, i0 = threadIdx.x >> 5;   // 8 rows per step
#pragma unroll
    for (int s = 0; s < 4; ++s) {
        int i = i0 + s * 8;
        t[i][j] = W[(size_t)(k0 + i) * M + m0 + j];
    }
    __syncthreads();
#pragma unroll
    for (int s = 0; s < 4; ++s) {
        int i = i0 + s * 8;                 // local m
        float v = t[j][i];                  // = W[k0+j][m0+i]
        bf16 hi = (bf16)v;
        bf16 lo = (bf16)(v - (float)hi);
        Th[(size_t)(m0 + i) * 1024 + k0 + j] = hi;
        Tl[(size_t)(m0 + i) * 1024 + k0 + j] = lo;
    }
}

// ---------------------------------------------------------------------------
// Split-bf16 3-pass MFMA GEMM: C[N,M] = (Ah+Al)[N,1024] * (Bh+Bl)[1024,M]
// A stored [N][1024] bf16 (row k-contig); B stored transposed [M][1024] bf16.
// 128x128 tile, BK=32, 4 waves (2x2 of 64x64), XOR-swizzled LDS.
__global__ __launch_bounds__(256, 2)
void k_gemm3(const bf16* __restrict__ Ah, const bf16* __restrict__ Al,
             const bf16* __restrict__ Bh, const bf16* __restrict__ Bl,
             float* __restrict__ C, int N, int M) {
    __shared__ __align__(16) bf16 sAh[128 * 32];
    __shared__ __align__(16) bf16 sAl[128 * 32];
    __shared__ __align__(16) bf16 sBh[128 * 32];
    __shared__ __align__(16) bf16 sBl[128 * 32];

    const int tid  = threadIdx.x;
    const int wid  = tid >> 6, lane = tid & 63;
    const int wr   = wid >> 1, wc = wid & 1;
    const int row0 = blockIdx.x * 128, col0 = blockIdx.y * 128;

    f32x4 acc[4][4] = {};

    // staging: wave stages rows [wid*32, wid*32+32) of each array (2 instrs)
    const int rl = lane >> 2;      // 0..15 row-within-instr
    const int gg = lane & 3;       // 16B chunk id
    const int rb0 = wid * 32;

    const int lrow = lane & 15, g4 = lane >> 4;

    for (int k0 = 0; k0 < 1024; k0 += 32) {
#pragma unroll
        for (int half = 0; half < 2; ++half) {
            int rt = rb0 + half * 16 + rl;              // tile row 0..127
            int kc = (gg ^ ((rt >> 1) & 3)) * 8;        // swizzled k chunk (elems)
            size_t lbase = (size_t)(rb0 + half * 16) * 32;  // elems
            int ar = row0 + rt; if (ar >= N) ar = N - 1;
            gll16(Ah + (size_t)ar * 1024 + k0 + kc, sAh + lbase);
            gll16(Al + (size_t)ar * 1024 + k0 + kc, sAl + lbase);
            int br = col0 + rt;
            gll16(Bh + (size_t)br * 1024 + k0 + kc, sBh + lbase);
            gll16(Bl + (size_t)br * 1024 + k0 + kc, sBl + lbase);
        }
        __syncthreads();   // drains vmcnt -> LDS ready

        bf16x8 ah[4], al[4], bh[4], bl[4];
#pragma unroll
        for (int m = 0; m < 4; ++m) {
            int r = wr * 64 + m * 16 + lrow;
            int off = r * 32 + ((g4 ^ ((r >> 1) & 3)) * 8);
            ah[m] = *(const bf16x8*)&sAh[off];
            al[m] = *(const bf16x8*)&sAl[off];
        }
#pragma unroll
        for (int n = 0; n < 4; ++n) {
            int r = wc * 64 + n * 16 + lrow;
            int off = r * 32 + ((g4 ^ ((r >> 1) & 3)) * 8);
            bh[n] = *(const bf16x8*)&sBh[off];
            bl[n] = *(const bf16x8*)&sBl[off];
        }
#pragma unroll
        for (int m = 0; m < 4; ++m)
#pragma unroll
            for (int n = 0; n < 4; ++n) {
                acc[m][n] = __builtin_amdgcn_mfma_f32_16x16x32_bf16(ah[m], bh[n], acc[m][n], 0, 0, 0);
                acc[m][n] = __builtin_amdgcn_mfma_f32_16x16x32_bf16(ah[m], bl[n], acc[m][n], 0, 0, 0);
                acc[m][n] = __builtin_amdgcn_mfma_f32_16x16x32_bf16(al[m], bh[n], acc[m][n], 0, 0, 0);
            }
        __syncthreads();
    }

    // epilogue: C/D layout col=lane&15, row=(lane>>4)*4+q
#pragma unroll
    for (int m = 0; m < 4; ++m) {
#pragma unroll
        for (int n = 0; n < 4; ++n) {
            int col = col0 + wc * 64 + n * 16 + lrow;
#pragma unroll
            for (int q = 0; q < 4; ++q) {
                int row = row0 + wr * 64 + m * 16 + g4 * 4 + q;
                if (row < N) C[(size_t)row * M + col] = acc[m][n][q];
            }
        }
    }
}

// ---------------------------------------------------------------------------
// alpha_s/alpha_d: one 64-lane wave per (node, head)
__global__ __launch_bounds__(256)
void k_alpha(const float* __restrict__ h, const float* __restrict__ a_s,
             const float* __restrict__ a_d, float* __restrict__ as_out,
             float* __restrict__ ad_out, int C, int M) {
    int pair = blockIdx.x * 4 + (threadIdx.x >> 6);
    int lane = threadIdx.x & 63;
    if (pair >= N_NODES * HEADS) return;
    int n = pair >> 4, hd = pair & 15;
    float vs = 0.f, vd = 0.f;
    if (lane < C) {
        float hv = h[(size_t)n * M + hd * C + lane];
        vs = hv * a_s[hd * C + lane];
        vd = hv * a_d[hd * C + lane];
    }
#pragma unroll
    for (int off = 32; off > 0; off >>= 1) {
        vs += __shfl_down(vs, off);
        vd += __shfl_down(vd, off);
    }
    if (lane == 0) { as_out[pair] = vs; ad_out[pair] = vd; }
}

// ---------------------------------------------------------------------------
// per-edge pre-softmax logits (leaky relu)
__global__ __launch_bounds__(256)
void k_edge(const int* __restrict__ ei, const float* __restrict__ as_,
            const float* __restrict__ ad_, float* __restrict__ ev) {
    int t = blockIdx.x * 256 + threadIdx.x;
    if (t >= E_TOT * HEADS) return;
    int e = t >> 4, hd = t & 15;
    int s, d;
    if (e < N_EDGES) { s = ei[e]; d = ei[N_EDGES + e]; }
    else             { s = d = e - N_EDGES; }
    float v = as_[s * 16 + hd] + ad_[d * 16 + hd];
    ev[t] = v > 0.f ? v : 0.2f * v;
}

// ---------------------------------------------------------------------------
// CSR build
__global__ void k_zero_i(int* __restrict__ p, int n) {
    int t = blockIdx.x * 256 + threadIdx.x;
    if (t < n) p[t] = 0;
}
__global__ void k_hist(const int* __restrict__ ei, int* __restrict__ deg) {
    int e = blockIdx.x * 256 + threadIdx.x;
    if (e >= E_TOT) return;
    int d = (e < N_EDGES) ? ei[N_EDGES + e] : e - N_EDGES;
    atomicAdd(&deg[d], 1);
}
__global__ __launch_bounds__(256)
void k_scan(const int* __restrict__ deg, int* __restrict__ rowstart,
            int* __restrict__ cursor) {
    __shared__ int sh[256];
    int carry = 0;
    for (int base = 0; base < N_NODES; base += 256) {
        int i = base + threadIdx.x;
        int v = (i < N_NODES) ? deg[i] : 0;
        sh[threadIdx.x] = v;
        __syncthreads();
        for (int off = 1; off < 256; off <<= 1) {
            int t = (threadIdx.x >= off) ? sh[threadIdx.x - off] : 0;
            __syncthreads();
            sh[threadIdx.x] += t;
            __syncthreads();
        }
        if (i < N_NODES) {
            int excl = carry + sh[threadIdx.x] - v;
            rowstart[i] = excl;
            cursor[i] = excl;
        }
        carry += sh[255];
        __syncthreads();
    }
    if (threadIdx.x == 0) rowstart[N_NODES] = carry;
}
__global__ void k_scatter(const int* __restrict__ ei, int* __restrict__ cursor,
                          int* __restrict__ csr_src, int* __restrict__ csr_eid) {
    int e = blockIdx.x * 256 + threadIdx.x;
    if (e >= E_TOT) return;
    int s, d;
    if (e < N_EDGES) { s = ei[e]; d = ei[N_EDGES + e]; }
    else             { s = d = e - N_EDGES; }
    int slot = atomicAdd(&cursor[d], 1);
    csr_src[slot] = s;
    csr_eid[slot] = e;
}

// ---------------------------------------------------------------------------
// segment softmax per (node, head), in place on ev
__global__ __launch_bounds__(256)
void k_softmax(const int* __restrict__ rowstart, const int* __restrict__ csr_eid,
               float* __restrict__ ev) {
    int t = blockIdx.x * 256 + threadIdx.x;
    if (t >= N_NODES * HEADS) return;
    int n = t >> 4, hd = t & 15;
    int s0 = rowstart[n], s1 = rowstart[n + 1];
    float m = -1e30f;
    for (int j = s0; j < s1; ++j) m = fmaxf(m, ev[csr_eid[j] * 16 + hd]);
    float den = 0.f;
    for (int j = s0; j < s1; ++j) den += __expf(ev[csr_eid[j] * 16 + hd] - m);
    float inv = 1.f / (den + 1e-16f);
    for (int j = s0; j < s1; ++j) {
        int idx = csr_eid[j] * 16 + hd;
        ev[idx] = __expf(ev[idx] - m) * inv;
    }
}

// ---------------------------------------------------------------------------
// aggregation M=1024: out = relu(sum alpha*h[src] + bias), written as bf16 hi/lo
__global__ __launch_bounds__(256)
void k_agg1024_bf(const float* __restrict__ h, const float* __restrict__ alpha,
                  const int* __restrict__ rowstart, const int* __restrict__ csr_src,
                  const int* __restrict__ csr_eid, const float* __restrict__ bias,
                  bf16* __restrict__ oh, bf16* __restrict__ ol) {
    int n = blockIdx.x;
    int s0 = rowstart[n], s1 = rowstart[n + 1];
    int t = threadIdx.x;
    int f0 = t * 4;
    int hd = f0 >> 6;
    float4 acc = {0.f, 0.f, 0.f, 0.f};
    for (int j = s0; j < s1; ++j) {
        int src = csr_src[j];
        int eid = csr_eid[j];
        float a = alpha[(size_t)eid * 16 + hd];
        float4 hv = *reinterpret_cast<const float4*>(&h[(size_t)src * 1024 + f0]);
        acc.x = fmaf(a, hv.x, acc.x);
        acc.y = fmaf(a, hv.y, acc.y);
        acc.z = fmaf(a, hv.z, acc.z);
        acc.w = fmaf(a, hv.w, acc.w);
    }
    float4 bv = *reinterpret_cast<const float4*>(&bias[f0]);
    float v[4] = {acc.x + bv.x, acc.y + bv.y, acc.z + bv.z, acc.w + bv.w};
    bf16x4 vh, vl;
#pragma unroll
    for (int c = 0; c < 4; ++c) {
        float r = fmaxf(v[c], 0.f);
        bf16 hi = (bf16)r;
        vh[c] = hi;
        vl[c] = (bf16)(r - (float)hi);
    }
    *reinterpret_cast<bf16x4*>(&oh[(size_t)n * 1024 + f0]) = vh;
    *reinterpret_cast<bf16x4*>(&ol[(size_t)n * 1024 + f0]) = vl;
}

// last layer M=768 (C=48): fp32 out, no relu
__global__ __launch_bounds__(256)
void k_agg768(const float* __restrict__ h, const float* __restrict__ alpha,
              const int* __restrict__ rowstart, const int* __restrict__ csr_src,
              const int* __restrict__ csr_eid, const float* __restrict__ bias,
              float* __restrict__ out) {
    int n = blockIdx.x;
    int s0 = rowstart[n], s1 = rowstart[n + 1];
    int t = threadIdx.x;
    float acc[3] = {0.f, 0.f, 0.f};
    int hd[3];
#pragma unroll
    for (int i = 0; i < 3; ++i) hd[i] = (t + i * 256) / 48;
    for (int j = s0; j < s1; ++j) {
        int src = csr_src[j];
        int eid = csr_eid[j];
        const float* hrow = h + (size_t)src * 768;
        const float* al = alpha + (size_t)eid * 16;
#pragma unroll
        for (int i = 0; i < 3; ++i)
            acc[i] = fmaf(al[hd[i]], hrow[t + i * 256], acc[i]);
    }
#pragma unroll
    for (int i = 0; i < 3; ++i) {
        int f = t + i * 256;
        out[(size_t)n * 768 + f] = acc[i] + bias[f];
    }
}

// ---------------------------------------------------------------------------
// final: out[1,768] = sum_n x[n, :]
__global__ __launch_bounds__(256)
void k_colsum(const float* __restrict__ x, float* __restrict__ out) {
    int f = blockIdx.x * 256 + threadIdx.x;
    int chunk = blockIdx.y;
    int n0 = chunk * 625, n1 = n0 + 625;
    float s = 0.f;
    for (int n = n0; n < n1; ++n) s += x[(size_t)n * 768 + f];
    atomicAdd(&out[f], s);
}

// ---------------------------------------------------------------------------
extern "C" void kernel_launch(void* const* d_in, const int* in_sizes, int n_in,
                              void* d_out, int out_size, void* d_ws, size_t ws_size,
                              hipStream_t stream) {
    const float* x0 = (const float*)d_in[0];
    const int*   ei = (const int*)d_in[1];

    // workspace carve
    char* w = (char*)d_ws;
    bf16*  x_hi = (bf16*)w;                       // [N,1024]
    bf16*  x_lo = x_hi + (size_t)N_NODES * 1024;  // [N,1024]
    float* xOut = (float*)w;                      // alias: layer-6 out [N,768]
    w += (size_t)N_NODES * 1024 * 2 * sizeof(bf16);
    float* xB = (float*)w; w += (size_t)N_NODES * 1024 * sizeof(float);
    float* ev = (float*)w; w += (size_t)E_TOT * HEADS * sizeof(float);
    float* as_ = (float*)w; w += (size_t)N_NODES * HEADS * sizeof(float);
    float* ad_ = (float*)w; w += (size_t)N_NODES * HEADS * sizeof(float);
    bf16* Wt_hi = (bf16*)w; w += (size_t)1024 * 1024 * sizeof(bf16);
    bf16* Wt_lo = (bf16*)w; w += (size_t)1024 * 1024 * sizeof(bf16);
    int* deg      = (int*)w; w += N_NODES * sizeof(int);
    int* rowstart = (int*)w; w += (N_NODES + 1) * sizeof(int);
    int* cursor   = (int*)w; w += N_NODES * sizeof(int);
    int* csr_src  = (int*)w; w += E_TOT * sizeof(int);
    int* csr_eid  = (int*)w; w += E_TOT * sizeof(int);

    // ---- CSR build (once) ----
    k_zero_i<<<(N_NODES + 255) / 256, 256, 0, stream>>>(deg, N_NODES);
    k_hist<<<(E_TOT + 255) / 256, 256, 0, stream>>>(ei, deg);
    k_scan<<<1, 256, 0, stream>>>(deg, rowstart, cursor);
    k_scatter<<<(E_TOT + 255) / 256, 256, 0, stream>>>(ei, cursor, csr_src, csr_eid);

    for (int l = 0; l < 6; ++l) {
        const float* W   = (const float*)d_in[2 + 4 * l + 0];
        const float* asv = (const float*)d_in[2 + 4 * l + 1];
        const float* adv = (const float*)d_in[2 + 4 * l + 2];
        const float* bv  = (const float*)d_in[2 + 4 * l + 3];
        int C = (l == 5) ? 48 : 64;
        int M = HEADS * C;   // 1024 or 768

        if (l == 0) {
            k_lin1<<<(N_NODES * 1024 + 255) / 256, 256, 0, stream>>>(x0, W, xB);
        } else {
            dim3 tg(M / 32, 32);
            k_convW<<<tg, 256, 0, stream>>>(W, Wt_hi, Wt_lo, M);
            dim3 grid((N_NODES + 127) / 128, M / 128);
            k_gemm3<<<grid, 256, 0, stream>>>(x_hi, x_lo, Wt_hi, Wt_lo, xB, N_NODES, M);
        }
        k_alpha<<<(N_NODES * HEADS + 3) / 4, 256, 0, stream>>>(xB, asv, adv, as_, ad_, C, M);
        k_edge<<<(E_TOT * HEADS + 255) / 256, 256, 0, stream>>>(ei, as_, ad_, ev);
        k_softmax<<<(N_NODES * HEADS + 255) / 256, 256, 0, stream>>>(rowstart, csr_eid, ev);
        if (M == 1024) {
            k_agg1024_bf<<<N_NODES, 256, 0, stream>>>(xB, ev, rowstart, csr_src, csr_eid, bv, x_hi, x_lo);
        } else {
            k_agg768<<<N_NODES, 256, 0, stream>>>(xB, ev, rowstart, csr_src, csr_eid, bv, xOut);
        }
    }

    hipMemsetAsync(d_out, 0, (size_t)out_size * sizeof(float), stream);
    dim3 cgrid(3, 32);
    k_colsum<<<cgrid, 256, 0, stream>>>(xOut, (float*)d_out);
}

// Round 3
// 1931.241 us; speedup vs baseline: 2.1632x; 1.4059x over previous
//
#include <hip/hip_runtime.h>
#include <cstddef>
#include <cstdint>

#define N_NODES 20000
#define N_EDGES 320000
#define E_TOT   (N_EDGES + N_NODES)   // 340000
#define HEADS   16

typedef __bf16 bf16;
typedef __attribute__((ext_vector_type(8))) __bf16 bf16x8;
typedef __attribute__((ext_vector_type(4))) float  f32x4;

__device__ __forceinline__ void gll16(const void* g, void* l) {
    __builtin_amdgcn_global_load_lds(
        (const __attribute__((address_space(1))) unsigned int*)g,
        (__attribute__((address_space(3))) unsigned int*)l, 16, 0, 0);
}

// ---------------------------------------------------------------------------
// Layer 1: x[N,3] @ W[3,1024] -> h fp32 + bf16 copy
__global__ __launch_bounds__(256)
void k_lin1(const float* __restrict__ x, const float* __restrict__ W,
            float* __restrict__ h, bf16* __restrict__ hg) {
    int idx = blockIdx.x * 256 + threadIdx.x;
    if (idx >= N_NODES * 1024) return;
    int n = idx >> 10, j = idx & 1023;
    float v = x[n*3+0]*W[j] + x[n*3+1]*W[1024+j] + x[n*3+2]*W[2048+j];
    h[idx] = v;
    hg[idx] = (bf16)v;
}

// ---------------------------------------------------------------------------
// W [1024][M] fp32 -> Wt_hi/Wt_lo [M][1024] bf16 (transpose + hi/lo split)
__global__ __launch_bounds__(256)
void k_convW(const float* __restrict__ W, bf16* __restrict__ Th,
             bf16* __restrict__ Tl, int M) {
    __shared__ float t[32][33];
    int m0 = blockIdx.x * 32, k0 = blockIdx.y * 32;
    int j = threadIdx.x & 31, i0 = threadIdx.x >> 5;
#pragma unroll
    for (int s = 0; s < 4; ++s) {
        int i = i0 + s * 8;
        t[i][j] = W[(size_t)(k0 + i) * M + m0 + j];
    }
    __syncthreads();
#pragma unroll
    for (int s = 0; s < 4; ++s) {
        int i = i0 + s * 8;
        float v = t[j][i];
        bf16 hi = (bf16)v;
        bf16 lo = (bf16)(v - (float)hi);
        Th[(size_t)(m0 + i) * 1024 + k0 + j] = hi;
        Tl[(size_t)(m0 + i) * 1024 + k0 + j] = lo;
    }
}

// ---------------------------------------------------------------------------
// Split-bf16 3-pass MFMA GEMM + bf16 gather-copy epilogue
__global__ __launch_bounds__(256, 2)
void k_gemm3(const bf16* __restrict__ Ah, const bf16* __restrict__ Al,
             const bf16* __restrict__ Bh, const bf16* __restrict__ Bl,
             float* __restrict__ C, bf16* __restrict__ Ch, int N, int M) {
    __shared__ __align__(16) bf16 sAh[128 * 32];
    __shared__ __align__(16) bf16 sAl[128 * 32];
    __shared__ __align__(16) bf16 sBh[128 * 32];
    __shared__ __align__(16) bf16 sBl[128 * 32];

    const int tid  = threadIdx.x;
    const int wid  = tid >> 6, lane = tid & 63;
    const int wr   = wid >> 1, wc = wid & 1;
    const int row0 = blockIdx.x * 128, col0 = blockIdx.y * 128;

    f32x4 acc[4][4] = {};

    const int rl = lane >> 2;
    const int gg = lane & 3;
    const int rb0 = wid * 32;
    const int lrow = lane & 15, g4 = lane >> 4;

    for (int k0 = 0; k0 < 1024; k0 += 32) {
#pragma unroll
        for (int half = 0; half < 2; ++half) {
            int rt = rb0 + half * 16 + rl;
            int kc = (gg ^ ((rt >> 1) & 3)) * 8;
            size_t lbase = (size_t)(rb0 + half * 16) * 32;
            int ar = row0 + rt; if (ar >= N) ar = N - 1;
            gll16(Ah + (size_t)ar * 1024 + k0 + kc, sAh + lbase);
            gll16(Al + (size_t)ar * 1024 + k0 + kc, sAl + lbase);
            int br = col0 + rt;
            gll16(Bh + (size_t)br * 1024 + k0 + kc, sBh + lbase);
            gll16(Bl + (size_t)br * 1024 + k0 + kc, sBl + lbase);
        }
        __syncthreads();

        bf16x8 ah[4], al[4], bh[4], bl[4];
#pragma unroll
        for (int m = 0; m < 4; ++m) {
            int r = wr * 64 + m * 16 + lrow;
            int off = r * 32 + ((g4 ^ ((r >> 1) & 3)) * 8);
            ah[m] = *(const bf16x8*)&sAh[off];
            al[m] = *(const bf16x8*)&sAl[off];
        }
#pragma unroll
        for (int n = 0; n < 4; ++n) {
            int r = wc * 64 + n * 16 + lrow;
            int off = r * 32 + ((g4 ^ ((r >> 1) & 3)) * 8);
            bh[n] = *(const bf16x8*)&sBh[off];
            bl[n] = *(const bf16x8*)&sBl[off];
        }
#pragma unroll
        for (int m = 0; m < 4; ++m)
#pragma unroll
            for (int n = 0; n < 4; ++n) {
                acc[m][n] = __builtin_amdgcn_mfma_f32_16x16x32_bf16(ah[m], bh[n], acc[m][n], 0, 0, 0);
                acc[m][n] = __builtin_amdgcn_mfma_f32_16x16x32_bf16(ah[m], bl[n], acc[m][n], 0, 0, 0);
                acc[m][n] = __builtin_amdgcn_mfma_f32_16x16x32_bf16(al[m], bh[n], acc[m][n], 0, 0, 0);
            }
        __syncthreads();
    }

#pragma unroll
    for (int m = 0; m < 4; ++m) {
#pragma unroll
        for (int n = 0; n < 4; ++n) {
            int col = col0 + wc * 64 + n * 16 + lrow;
#pragma unroll
            for (int q = 0; q < 4; ++q) {
                int row = row0 + wr * 64 + m * 16 + g4 * 4 + q;
                if (row < N) {
                    float v = acc[m][n][q];
                    C[(size_t)row * M + col] = v;
                    Ch[(size_t)row * M + col] = (bf16)v;
                }
            }
        }
    }
}

// ---------------------------------------------------------------------------
// alpha_s/alpha_d: one 64-lane wave per (node, head)
__global__ __launch_bounds__(256)
void k_alpha(const float* __restrict__ h, const float* __restrict__ a_s,
             const float* __restrict__ a_d, float* __restrict__ as_out,
             float* __restrict__ ad_out, int C, int M) {
    int pair = blockIdx.x * 4 + (threadIdx.x >> 6);
    int lane = threadIdx.x & 63;
    if (pair >= N_NODES * HEADS) return;
    int n = pair >> 4, hd = pair & 15;
    float vs = 0.f, vd = 0.f;
    if (lane < C) {
        float hv = h[(size_t)n * M + hd * C + lane];
        vs = hv * a_s[hd * C + lane];
        vd = hv * a_d[hd * C + lane];
    }
#pragma unroll
    for (int off = 32; off > 0; off >>= 1) {
        vs += __shfl_down(vs, off);
        vd += __shfl_down(vd, off);
    }
    if (lane == 0) { as_out[pair] = vs; ad_out[pair] = vd; }
}

// ---------------------------------------------------------------------------
// CSR build
__global__ void k_zero_i(int* __restrict__ p, int n) {
    int t = blockIdx.x * 256 + threadIdx.x;
    if (t < n) p[t] = 0;
}
__global__ void k_hist(const int* __restrict__ ei, int* __restrict__ deg) {
    int e = blockIdx.x * 256 + threadIdx.x;
    if (e >= E_TOT) return;
    int d = (e < N_EDGES) ? ei[N_EDGES + e] : e - N_EDGES;
    atomicAdd(&deg[d], 1);
}
__global__ __launch_bounds__(256)
void k_scan(const int* __restrict__ deg, int* __restrict__ rowstart,
            int* __restrict__ cursor) {
    __shared__ int sh[256];
    int carry = 0;
    for (int base = 0; base < N_NODES; base += 256) {
        int i = base + threadIdx.x;
        int v = (i < N_NODES) ? deg[i] : 0;
        sh[threadIdx.x] = v;
        __syncthreads();
        for (int off = 1; off < 256; off <<= 1) {
            int t = (threadIdx.x >= off) ? sh[threadIdx.x - off] : 0;
            __syncthreads();
            sh[threadIdx.x] += t;
            __syncthreads();
        }
        if (i < N_NODES) {
            int excl = carry + sh[threadIdx.x] - v;
            rowstart[i] = excl;
            cursor[i] = excl;
        }
        carry += sh[255];
        __syncthreads();
    }
    if (threadIdx.x == 0) rowstart[N_NODES] = carry;
}
__global__ void k_scatter(const int* __restrict__ ei, int* __restrict__ cursor,
                          int* __restrict__ csr_src) {
    int e = blockIdx.x * 256 + threadIdx.x;
    if (e >= E_TOT) return;
    int s, d;
    if (e < N_EDGES) { s = ei[e]; d = ei[N_EDGES + e]; }
    else             { s = d = e - N_EDGES; }
    int slot = atomicAdd(&cursor[d], 1);
    csr_src[slot] = s;
}

// ---------------------------------------------------------------------------
// attention stats: per (node,head) online max + denom over CSR row
__global__ __launch_bounds__(256)
void k_attn(const int* __restrict__ rowstart, const int* __restrict__ csr_src,
            const float* __restrict__ as_, const float* __restrict__ ad_,
            float* __restrict__ m_, float* __restrict__ inv_) {
    int t = blockIdx.x * 256 + threadIdx.x;
    if (t >= N_NODES * HEADS) return;
    int n = t >> 4, hd = t & 15;
    int s0 = rowstart[n], s1 = rowstart[n + 1];
    float adv = ad_[t];
    float m = -1e30f, den = 0.f;
    for (int j = s0; j < s1; ++j) {
        float v = as_[csr_src[j] * 16 + hd] + adv;
        v = v > 0.f ? v : 0.2f * v;
        if (v > m) { den = den * __expf(m - v) + 1.f; m = v; }
        else       { den += __expf(v - m); }
    }
    m_[t] = m;
    inv_[t] = 1.f / (den + 1e-16f);
}

// ---------------------------------------------------------------------------
// aggregation M=1024: bf16 gather, alpha recomputed on the fly.
// 2 nodes per 256-thread block; 128 threads/node, 8 bf16 per thread.
__global__ __launch_bounds__(256)
void k_agg1024(const bf16* __restrict__ hg, const int* __restrict__ rowstart,
               const int* __restrict__ csr_src, const float* __restrict__ as_,
               const float* __restrict__ ad_, const float* __restrict__ m_,
               const float* __restrict__ inv_, const float* __restrict__ bias,
               bf16* __restrict__ oh, bf16* __restrict__ ol) {
    int n = blockIdx.x * 2 + (threadIdx.x >> 7);
    int tloc = threadIdx.x & 127;
    int f0 = tloc * 8;
    int hd = tloc >> 3;            // 64 cols per head / 8 per thread
    int s0 = rowstart[n], s1 = rowstart[n + 1];
    float adv = ad_[n * 16 + hd];
    float mm  = m_[n * 16 + hd];
    float inv = inv_[n * 16 + hd];
    float acc[8] = {};
    for (int j = s0; j < s1; ++j) {
        int s = csr_src[j];
        float v = as_[s * 16 + hd] + adv;
        v = v > 0.f ? v : 0.2f * v;
        float a = __expf(v - mm) * inv;
        bf16x8 hv = *reinterpret_cast<const bf16x8*>(&hg[(size_t)s * 1024 + f0]);
#pragma unroll
        for (int c = 0; c < 8; ++c) acc[c] = fmaf(a, (float)hv[c], acc[c]);
    }
    bf16x8 vh, vl;
#pragma unroll
    for (int c = 0; c < 8; ++c) {
        float r = fmaxf(acc[c] + bias[f0 + c], 0.f);
        bf16 hi = (bf16)r;
        vh[c] = hi;
        vl[c] = (bf16)(r - (float)hi);
    }
    *reinterpret_cast<bf16x8*>(&oh[(size_t)n * 1024 + f0]) = vh;
    *reinterpret_cast<bf16x8*>(&ol[(size_t)n * 1024 + f0]) = vl;
}

// last layer M=768 (C=48): bf16 gather, fp32 out, no relu
__global__ __launch_bounds__(256)
void k_agg768(const bf16* __restrict__ hg, const int* __restrict__ rowstart,
              const int* __restrict__ csr_src, const float* __restrict__ as_,
              const float* __restrict__ ad_, const float* __restrict__ m_,
              const float* __restrict__ inv_, const float* __restrict__ bias,
              float* __restrict__ out) {
    int n = blockIdx.x * 2 + (threadIdx.x >> 7);
    int tloc = threadIdx.x & 127;
    if (tloc >= 96) return;
    int f0 = tloc * 8;
    int hd = f0 / 48;              // 8-elem chunk never crosses a head (48=6*8)
    int s0 = rowstart[n], s1 = rowstart[n + 1];
    float adv = ad_[n * 16 + hd];
    float mm  = m_[n * 16 + hd];
    float inv = inv_[n * 16 + hd];
    float acc[8] = {};
    for (int j = s0; j < s1; ++j) {
        int s = csr_src[j];
        float v = as_[s * 16 + hd] + adv;
        v = v > 0.f ? v : 0.2f * v;
        float a = __expf(v - mm) * inv;
        bf16x8 hv = *reinterpret_cast<const bf16x8*>(&hg[(size_t)s * 768 + f0]);
#pragma unroll
        for (int c = 0; c < 8; ++c) acc[c] = fmaf(a, (float)hv[c], acc[c]);
    }
#pragma unroll
    for (int c = 0; c < 8; ++c)
        out[(size_t)n * 768 + f0 + c] = acc[c] + bias[f0 + c];
}

// ---------------------------------------------------------------------------
// final: out[1,768] = sum_n x[n, :]
__global__ __launch_bounds__(256)
void k_colsum(const float* __restrict__ x, float* __restrict__ out) {
    int f = blockIdx.x * 256 + threadIdx.x;
    int chunk = blockIdx.y;
    int n0 = chunk * 625, n1 = n0 + 625;
    float s = 0.f;
    for (int n = n0; n < n1; ++n) s += x[(size_t)n * 768 + f];
    atomicAdd(&out[f], s);
}

// ---------------------------------------------------------------------------
extern "C" void kernel_launch(void* const* d_in, const int* in_sizes, int n_in,
                              void* d_out, int out_size, void* d_ws, size_t ws_size,
                              hipStream_t stream) {
    const float* x0 = (const float*)d_in[0];
    const int*   ei = (const int*)d_in[1];

    char* w = (char*)d_ws;
    float* xB  = (float*)w; w += (size_t)N_NODES * 1024 * sizeof(float);
    bf16*  hgat = (bf16*)w; w += (size_t)N_NODES * 1024 * sizeof(bf16);
    bf16*  x_hi = (bf16*)w;                       // also aliased by xOut
    float* xOut = (float*)w;                      // [N,768] fp32, layer-6 out
    w += (size_t)N_NODES * 1024 * sizeof(bf16);
    bf16*  x_lo = (bf16*)w; w += (size_t)N_NODES * 1024 * sizeof(bf16);
    float* as_  = (float*)w; w += (size_t)N_NODES * HEADS * sizeof(float);
    float* ad_  = (float*)w; w += (size_t)N_NODES * HEADS * sizeof(float);
    float* m_   = (float*)w; w += (size_t)N_NODES * HEADS * sizeof(float);
    float* inv_ = (float*)w; w += (size_t)N_NODES * HEADS * sizeof(float);
    bf16* Wt_hi = (bf16*)w; w += (size_t)1024 * 1024 * sizeof(bf16);
    bf16* Wt_lo = (bf16*)w; w += (size_t)1024 * 1024 * sizeof(bf16);
    int* deg      = (int*)w; w += N_NODES * sizeof(int);
    int* rowstart = (int*)w; w += (N_NODES + 1) * sizeof(int);
    int* cursor   = (int*)w; w += N_NODES * sizeof(int);
    int* csr_src  = (int*)w; w += E_TOT * sizeof(int);

    // ---- CSR build (once) ----
    k_zero_i<<<(N_NODES + 255) / 256, 256, 0, stream>>>(deg, N_NODES);
    k_hist<<<(E_TOT + 255) / 256, 256, 0, stream>>>(ei, deg);
    k_scan<<<1, 256, 0, stream>>>(deg, rowstart, cursor);
    k_scatter<<<(E_TOT + 255) / 256, 256, 0, stream>>>(ei, cursor, csr_src);

    for (int l = 0; l < 6; ++l) {
        const float* W   = (const float*)d_in[2 + 4 * l + 0];
        const float* asv = (const float*)d_in[2 + 4 * l + 1];
        const float* adv = (const float*)d_in[2 + 4 * l + 2];
        const float* bv  = (const float*)d_in[2 + 4 * l + 3];
        int C = (l == 5) ? 48 : 64;
        int M = HEADS * C;   // 1024 or 768

        if (l == 0) {
            k_lin1<<<(N_NODES * 1024 + 255) / 256, 256, 0, stream>>>(x0, W, xB, hgat);
        } else {
            dim3 tg(M / 32, 32);
            k_convW<<<tg, 256, 0, stream>>>(W, Wt_hi, Wt_lo, M);
            dim3 grid((N_NODES + 127) / 128, M / 128);
            k_gemm3<<<grid, 256, 0, stream>>>(x_hi, x_lo, Wt_hi, Wt_lo, xB, hgat, N_NODES, M);
        }
        k_alpha<<<(N_NODES * HEADS + 3) / 4, 256, 0, stream>>>(xB, asv, adv, as_, ad_, C, M);
        k_attn<<<(N_NODES * HEADS + 255) / 256, 256, 0, stream>>>(rowstart, csr_src, as_, ad_, m_, inv_);
        if (M == 1024) {
            k_agg1024<<<N_NODES / 2, 256, 0, stream>>>(hgat, rowstart, csr_src, as_, ad_, m_, inv_, bv, x_hi, x_lo);
        } else {
            k_agg768<<<N_NODES / 2, 256, 0, stream>>>(hgat, rowstart, csr_src, as_, ad_, m_, inv_, bv, xOut);
        }
    }

    hipMemsetAsync(d_out, 0, (size_t)out_size * sizeof(float), stream);
    dim3 cgrid(3, 32);
    k_colsum<<<cgrid, 256, 0, stream>>>(xOut, (float*)d_out);
}

// Round 4
// 1518.232 us; speedup vs baseline: 2.7517x; 1.2720x over previous
//
#include <hip/hip_runtime.h>
#include <cstddef>
#include <cstdint>

#define N_NODES 20000
#define N_EDGES 320000
#define E_TOT   (N_EDGES + N_NODES)   // 340000
#define HEADS   16

typedef __bf16 bf16;
typedef __attribute__((ext_vector_type(8))) __bf16 bf16x8;
typedef __attribute__((ext_vector_type(4))) __bf16 bf16x4;
typedef __attribute__((ext_vector_type(4))) float  f32x4;

__device__ __forceinline__ void gll16(const void* g, void* l) {
    __builtin_amdgcn_global_load_lds(
        (const __attribute__((address_space(1))) unsigned int*)g,
        (__attribute__((address_space(3))) unsigned int*)l, 16, 0, 0);
}

// ---------------------------------------------------------------------------
// Layer 1: x[N,3] @ W[3,1024] -> hgat bf16, fused alpha_s/alpha_d.
// One block per node; thread owns 4 cols; head = t>>4 (16 thr * 4 cols = 64).
__global__ __launch_bounds__(256)
void k_lin1(const float* __restrict__ x, const float* __restrict__ W,
            const float* __restrict__ aS, const float* __restrict__ aD,
            bf16* __restrict__ hg, float* __restrict__ as_,
            float* __restrict__ ad_) {
    int n = blockIdx.x;
    int t = threadIdx.x;
    int f0 = t * 4, hd = t >> 4;
    float x0 = x[n*3+0], x1 = x[n*3+1], x2 = x[n*3+2];
    float v[4];
    bf16x4 hv;
#pragma unroll
    for (int c = 0; c < 4; ++c) {
        int f = f0 + c;
        v[c] = x0*W[f] + x1*W[1024+f] + x2*W[2048+f];
        hv[c] = (bf16)v[c];
    }
    *reinterpret_cast<bf16x4*>(&hg[(size_t)n * 1024 + f0]) = hv;
    float ps = 0.f, pd = 0.f;
    int cb = (t & 15) * 4;
#pragma unroll
    for (int c = 0; c < 4; ++c) {
        ps = fmaf(v[c], aS[hd*64 + cb + c], ps);
        pd = fmaf(v[c], aD[hd*64 + cb + c], pd);
    }
#pragma unroll
    for (int off = 1; off < 16; off <<= 1) {
        ps += __shfl_xor(ps, off);
        pd += __shfl_xor(pd, off);
    }
    if ((t & 15) == 0) {
        as_[n*16 + hd] = ps;
        ad_[n*16 + hd] = pd;
    }
}

// ---------------------------------------------------------------------------
// W [1024][M] fp32 -> Wt_hi/Wt_lo [M][1024] bf16 (transpose + hi/lo split)
__global__ __launch_bounds__(256)
void k_convW(const float* __restrict__ W, bf16* __restrict__ Th,
             bf16* __restrict__ Tl, int M) {
    __shared__ float t[32][33];
    int m0 = blockIdx.x * 32, k0 = blockIdx.y * 32;
    int j = threadIdx.x & 31, i0 = threadIdx.x >> 5;
#pragma unroll
    for (int s = 0; s < 4; ++s) {
        int i = i0 + s * 8;
        t[i][j] = W[(size_t)(k0 + i) * M + m0 + j];
    }
    __syncthreads();
#pragma unroll
    for (int s = 0; s < 4; ++s) {
        int i = i0 + s * 8;
        float v = t[j][i];
        bf16 hi = (bf16)v;
        bf16 lo = (bf16)(v - (float)hi);
        Th[(size_t)(m0 + i) * 1024 + k0 + j] = hi;
        Tl[(size_t)(m0 + i) * 1024 + k0 + j] = lo;
    }
}

// ---------------------------------------------------------------------------
// Split-bf16 3-pass MFMA GEMM. blockIdx.x = COL block (8-wide -> XCD-pinned B),
// blockIdx.y = row block. FUSE: alpha epilogue (C=64 layers), no fp32 C write.
template<bool FUSE>
__global__ __launch_bounds__(256, 2)
void k_gemm3(const bf16* __restrict__ Ah, const bf16* __restrict__ Al,
             const bf16* __restrict__ Bh, const bf16* __restrict__ Bl,
             float* __restrict__ Cf, bf16* __restrict__ Ch,
             const float* __restrict__ aS, const float* __restrict__ aD,
             float* __restrict__ as_, float* __restrict__ ad_,
             int N, int M) {
    __shared__ __align__(16) bf16 sAh[128 * 32];
    __shared__ __align__(16) bf16 sAl[128 * 32];
    __shared__ __align__(16) bf16 sBh[128 * 32];
    __shared__ __align__(16) bf16 sBl[128 * 32];

    const int tid  = threadIdx.x;
    const int wid  = tid >> 6, lane = tid & 63;
    const int wr   = wid >> 1, wc = wid & 1;
    const int col0 = blockIdx.x * 128, row0 = blockIdx.y * 128;

    f32x4 acc[4][4] = {};

    const int rl = lane >> 2;
    const int gg = lane & 3;
    const int rb0 = wid * 32;
    const int lrow = lane & 15, g4 = lane >> 4;

    for (int k0 = 0; k0 < 1024; k0 += 32) {
#pragma unroll
        for (int half = 0; half < 2; ++half) {
            int rt = rb0 + half * 16 + rl;
            int kc = (gg ^ ((rt >> 1) & 3)) * 8;
            size_t lbase = (size_t)(rb0 + half * 16) * 32;
            int ar = row0 + rt; if (ar >= N) ar = N - 1;
            gll16(Ah + (size_t)ar * 1024 + k0 + kc, sAh + lbase);
            gll16(Al + (size_t)ar * 1024 + k0 + kc, sAl + lbase);
            int br = col0 + rt;
            gll16(Bh + (size_t)br * 1024 + k0 + kc, sBh + lbase);
            gll16(Bl + (size_t)br * 1024 + k0 + kc, sBl + lbase);
        }
        __syncthreads();

        bf16x8 ah[4], al[4], bh[4], bl[4];
#pragma unroll
        for (int m = 0; m < 4; ++m) {
            int r = wr * 64 + m * 16 + lrow;
            int off = r * 32 + ((g4 ^ ((r >> 1) & 3)) * 8);
            ah[m] = *(const bf16x8*)&sAh[off];
            al[m] = *(const bf16x8*)&sAl[off];
        }
#pragma unroll
        for (int n = 0; n < 4; ++n) {
            int r = wc * 64 + n * 16 + lrow;
            int off = r * 32 + ((g4 ^ ((r >> 1) & 3)) * 8);
            bh[n] = *(const bf16x8*)&sBh[off];
            bl[n] = *(const bf16x8*)&sBl[off];
        }
#pragma unroll
        for (int m = 0; m < 4; ++m)
#pragma unroll
            for (int n = 0; n < 4; ++n) {
                acc[m][n] = __builtin_amdgcn_mfma_f32_16x16x32_bf16(ah[m], bh[n], acc[m][n], 0, 0, 0);
                acc[m][n] = __builtin_amdgcn_mfma_f32_16x16x32_bf16(ah[m], bl[n], acc[m][n], 0, 0, 0);
                acc[m][n] = __builtin_amdgcn_mfma_f32_16x16x32_bf16(al[m], bh[n], acc[m][n], 0, 0, 0);
            }
        __syncthreads();
    }

    // C/D layout: col=lane&15 (lrow), row=(lane>>4)*4+q (g4,q)
#pragma unroll
    for (int m = 0; m < 4; ++m) {
#pragma unroll
        for (int n = 0; n < 4; ++n) {
            int col = col0 + wc * 64 + n * 16 + lrow;
#pragma unroll
            for (int q = 0; q < 4; ++q) {
                int row = row0 + wr * 64 + m * 16 + g4 * 4 + q;
                if (row < N) {
                    float v = acc[m][n][q];
                    if (!FUSE) Cf[(size_t)row * M + col] = v;
                    Ch[(size_t)row * M + col] = (bf16)v;
                }
            }
        }
    }

    if (FUSE) {
        // wave's 64 cols == one head (C=64): hd = col0/64 + wc
        const int hd = blockIdx.x * 2 + wc;
        float asv[4], adv[4];
#pragma unroll
        for (int n = 0; n < 4; ++n) {
            asv[n] = aS[hd * 64 + n * 16 + lrow];
            adv[n] = aD[hd * 64 + n * 16 + lrow];
        }
        float ps[4][4], pd[4][4];
#pragma unroll
        for (int m = 0; m < 4; ++m)
#pragma unroll
            for (int q = 0; q < 4; ++q) {
                float s = 0.f, d = 0.f;
#pragma unroll
                for (int n = 0; n < 4; ++n) {
                    s = fmaf(acc[m][n][q], asv[n], s);
                    d = fmaf(acc[m][n][q], adv[n], d);
                }
                ps[m][q] = s; pd[m][q] = d;
            }
#pragma unroll
        for (int off = 1; off < 16; off <<= 1) {
#pragma unroll
            for (int m = 0; m < 4; ++m)
#pragma unroll
                for (int q = 0; q < 4; ++q) {
                    ps[m][q] += __shfl_xor(ps[m][q], off);
                    pd[m][q] += __shfl_xor(pd[m][q], off);
                }
        }
        if (lrow == 0) {
#pragma unroll
            for (int m = 0; m < 4; ++m)
#pragma unroll
                for (int q = 0; q < 4; ++q) {
                    int row = row0 + wr * 64 + m * 16 + g4 * 4 + q;
                    if (row < N) {
                        as_[row * 16 + hd] = ps[m][q];
                        ad_[row * 16 + hd] = pd[m][q];
                    }
                }
        }
    }
}

// ---------------------------------------------------------------------------
// alpha for layer 6 only (C=48): one wave per (node, head)
__global__ __launch_bounds__(256)
void k_alpha(const float* __restrict__ h, const float* __restrict__ a_s,
             const float* __restrict__ a_d, float* __restrict__ as_out,
             float* __restrict__ ad_out, int C, int M) {
    int pair = blockIdx.x * 4 + (threadIdx.x >> 6);
    int lane = threadIdx.x & 63;
    if (pair >= N_NODES * HEADS) return;
    int n = pair >> 4, hd = pair & 15;
    float vs = 0.f, vd = 0.f;
    if (lane < C) {
        float hv = h[(size_t)n * M + hd * C + lane];
        vs = hv * a_s[hd * C + lane];
        vd = hv * a_d[hd * C + lane];
    }
#pragma unroll
    for (int off = 32; off > 0; off >>= 1) {
        vs += __shfl_down(vs, off);
        vd += __shfl_down(vd, off);
    }
    if (lane == 0) { as_out[pair] = vs; ad_out[pair] = vd; }
}

// ---------------------------------------------------------------------------
// CSR build
__global__ void k_zero_i(int* __restrict__ p, int n) {
    int t = blockIdx.x * 256 + threadIdx.x;
    if (t < n) p[t] = 0;
}
__global__ void k_hist(const int* __restrict__ ei, int* __restrict__ deg) {
    int e = blockIdx.x * 256 + threadIdx.x;
    if (e >= E_TOT) return;
    int d = (e < N_EDGES) ? ei[N_EDGES + e] : e - N_EDGES;
    atomicAdd(&deg[d], 1);
}
__global__ __launch_bounds__(256)
void k_scan(const int* __restrict__ deg, int* __restrict__ rowstart,
            int* __restrict__ cursor) {
    __shared__ int sh[256];
    int carry = 0;
    for (int base = 0; base < N_NODES; base += 256) {
        int i = base + threadIdx.x;
        int v = (i < N_NODES) ? deg[i] : 0;
        sh[threadIdx.x] = v;
        __syncthreads();
        for (int off = 1; off < 256; off <<= 1) {
            int t = (threadIdx.x >= off) ? sh[threadIdx.x - off] : 0;
            __syncthreads();
            sh[threadIdx.x] += t;
            __syncthreads();
        }
        if (i < N_NODES) {
            int excl = carry + sh[threadIdx.x] - v;
            rowstart[i] = excl;
            cursor[i] = excl;
        }
        carry += sh[255];
        __syncthreads();
    }
    if (threadIdx.x == 0) rowstart[N_NODES] = carry;
}
__global__ void k_scatter(const int* __restrict__ ei, int* __restrict__ cursor,
                          int* __restrict__ csr_src) {
    int e = blockIdx.x * 256 + threadIdx.x;
    if (e >= E_TOT) return;
    int s, d;
    if (e < N_EDGES) { s = ei[e]; d = ei[N_EDGES + e]; }
    else             { s = d = e - N_EDGES; }
    int slot = atomicAdd(&cursor[d], 1);
    csr_src[slot] = s;
}

// ---------------------------------------------------------------------------
// aggregation M=1024, ONLINE softmax fused into the gather loop.
// 2 nodes / 256-thr block; 128 thr/node; thread owns 8 cols; hd = tloc>>3.
__global__ __launch_bounds__(256)
void k_agg1024(const bf16* __restrict__ hg, const int* __restrict__ rowstart,
               const int* __restrict__ csr_src, const float* __restrict__ as_,
               const float* __restrict__ ad_, const float* __restrict__ bias,
               bf16* __restrict__ oh, bf16* __restrict__ ol) {
    int n = blockIdx.x * 2 + (threadIdx.x >> 7);
    int tloc = threadIdx.x & 127;
    int f0 = tloc * 8;
    int hd = tloc >> 3;
    int s0 = rowstart[n], s1 = rowstart[n + 1];
    float adv = ad_[n * 16 + hd];
    float m = -1e30f, den = 0.f;
    float acc[8] = {};
    for (int j = s0; j < s1; ++j) {
        int s = csr_src[j];
        float v = as_[s * 16 + hd] + adv;
        v = v > 0.f ? v : 0.2f * v;
        bf16x8 hv = *reinterpret_cast<const bf16x8*>(&hg[(size_t)s * 1024 + f0]);
        float nm = fmaxf(m, v);
        float rm = __expf(m - nm);
        float re = __expf(v - nm);
        den = den * rm + re;
#pragma unroll
        for (int c = 0; c < 8; ++c)
            acc[c] = fmaf(acc[c], rm, re * (float)hv[c]);
        m = nm;
    }
    float inv = 1.f / (den + 1e-16f);
    bf16x8 vh, vl;
#pragma unroll
    for (int c = 0; c < 8; ++c) {
        float r = fmaxf(fmaf(acc[c], inv, bias[f0 + c]), 0.f);
        bf16 hi = (bf16)r;
        vh[c] = hi;
        vl[c] = (bf16)(r - (float)hi);
    }
    *reinterpret_cast<bf16x8*>(&oh[(size_t)n * 1024 + f0]) = vh;
    *reinterpret_cast<bf16x8*>(&ol[(size_t)n * 1024 + f0]) = vl;
}

// last layer M=768 (C=48): online softmax, fp32 out, no relu
__global__ __launch_bounds__(256)
void k_agg768(const bf16* __restrict__ hg, const int* __restrict__ rowstart,
              const int* __restrict__ csr_src, const float* __restrict__ as_,
              const float* __restrict__ ad_, const float* __restrict__ bias,
              float* __restrict__ out) {
    int n = blockIdx.x * 2 + (threadIdx.x >> 7);
    int tloc = threadIdx.x & 127;
    if (tloc >= 96) return;
    int f0 = tloc * 8;
    int hd = f0 / 48;
    int s0 = rowstart[n], s1 = rowstart[n + 1];
    float adv = ad_[n * 16 + hd];
    float m = -1e30f, den = 0.f;
    float acc[8] = {};
    for (int j = s0; j < s1; ++j) {
        int s = csr_src[j];
        float v = as_[s * 16 + hd] + adv;
        v = v > 0.f ? v : 0.2f * v;
        bf16x8 hv = *reinterpret_cast<const bf16x8*>(&hg[(size_t)s * 768 + f0]);
        float nm = fmaxf(m, v);
        float rm = __expf(m - nm);
        float re = __expf(v - nm);
        den = den * rm + re;
#pragma unroll
        for (int c = 0; c < 8; ++c)
            acc[c] = fmaf(acc[c], rm, re * (float)hv[c]);
        m = nm;
    }
    float inv = 1.f / (den + 1e-16f);
#pragma unroll
    for (int c = 0; c < 8; ++c)
        out[(size_t)n * 768 + f0 + c] = fmaf(acc[c], inv, bias[f0 + c]);
}

// ---------------------------------------------------------------------------
// final: out[1,768] = sum_n x[n, :]
__global__ __launch_bounds__(256)
void k_colsum(const float* __restrict__ x, float* __restrict__ out) {
    int f = blockIdx.x * 256 + threadIdx.x;
    int chunk = blockIdx.y;
    int n0 = chunk * 625, n1 = n0 + 625;
    float s = 0.f;
    for (int n = n0; n < n1; ++n) s += x[(size_t)n * 768 + f];
    atomicAdd(&out[f], s);
}

// ---------------------------------------------------------------------------
extern "C" void kernel_launch(void* const* d_in, const int* in_sizes, int n_in,
                              void* d_out, int out_size, void* d_ws, size_t ws_size,
                              hipStream_t stream) {
    const float* x0 = (const float*)d_in[0];
    const int*   ei = (const int*)d_in[1];

    char* w = (char*)d_ws;
    float* xB  = (float*)w; w += (size_t)N_NODES * 1024 * sizeof(float);   // layer-6 fp32 C
    bf16*  hgat = (bf16*)w; w += (size_t)N_NODES * 1024 * sizeof(bf16);
    bf16*  x_hi = (bf16*)w;
    float* xOut = (float*)w;                      // alias: layer-6 agg out [N,768] fp32
    w += (size_t)N_NODES * 1024 * sizeof(bf16);
    bf16*  x_lo = (bf16*)w; w += (size_t)N_NODES * 1024 * sizeof(bf16);
    float* as_  = (float*)w; w += (size_t)N_NODES * HEADS * sizeof(float);
    float* ad_  = (float*)w; w += (size_t)N_NODES * HEADS * sizeof(float);
    bf16* Wt_hi = (bf16*)w; w += (size_t)1024 * 1024 * sizeof(bf16);
    bf16* Wt_lo = (bf16*)w; w += (size_t)1024 * 1024 * sizeof(bf16);
    int* deg      = (int*)w; w += N_NODES * sizeof(int);
    int* rowstart = (int*)w; w += (N_NODES + 1) * sizeof(int);
    int* cursor   = (int*)w; w += N_NODES * sizeof(int);
    int* csr_src  = (int*)w; w += E_TOT * sizeof(int);

    // ---- CSR build (once) ----
    k_zero_i<<<(N_NODES + 255) / 256, 256, 0, stream>>>(deg, N_NODES);
    k_hist<<<(E_TOT + 255) / 256, 256, 0, stream>>>(ei, deg);
    k_scan<<<1, 256, 0, stream>>>(deg, rowstart, cursor);
    k_scatter<<<(E_TOT + 255) / 256, 256, 0, stream>>>(ei, cursor, csr_src);

    for (int l = 0; l < 6; ++l) {
        const float* W  = (const float*)d_in[2 + 4 * l + 0];
        const float* aS = (const float*)d_in[2 + 4 * l + 1];
        const float* aD = (const float*)d_in[2 + 4 * l + 2];
        const float* bv = (const float*)d_in[2 + 4 * l + 3];
        int M = (l == 5) ? 768 : 1024;

        if (l == 0) {
            k_lin1<<<N_NODES, 256, 0, stream>>>(x0, W, aS, aD, hgat, as_, ad_);
        } else {
            dim3 tg(M / 32, 32);
            k_convW<<<tg, 256, 0, stream>>>(W, Wt_hi, Wt_lo, M);
            dim3 grid(M / 128, (N_NODES + 127) / 128);   // x = COL block
            if (l < 5) {
                k_gemm3<true><<<grid, 256, 0, stream>>>(
                    x_hi, x_lo, Wt_hi, Wt_lo, nullptr, hgat, aS, aD, as_, ad_,
                    N_NODES, M);
            } else {
                k_gemm3<false><<<grid, 256, 0, stream>>>(
                    x_hi, x_lo, Wt_hi, Wt_lo, xB, hgat, nullptr, nullptr,
                    nullptr, nullptr, N_NODES, M);
                k_alpha<<<(N_NODES * HEADS + 3) / 4, 256, 0, stream>>>(
                    xB, aS, aD, as_, ad_, 48, 768);
            }
        }
        if (l < 5) {
            k_agg1024<<<N_NODES / 2, 256, 0, stream>>>(
                hgat, rowstart, csr_src, as_, ad_, bv, x_hi, x_lo);
        } else {
            k_agg768<<<N_NODES / 2, 256, 0, stream>>>(
                hgat, rowstart, csr_src, as_, ad_, bv, xOut);
        }
    }

    hipMemsetAsync(d_out, 0, (size_t)out_size * sizeof(float), stream);
    dim3 cgrid(3, 32);
    k_colsum<<<cgrid, 256, 0, stream>>>(xOut, (float*)d_out);
}

// Round 6
// 1316.402 us; speedup vs baseline: 3.1735x; 1.1533x over previous
//
#include <hip/hip_runtime.h>
#include <cstddef>
#include <cstdint>

#define N_NODES 20000
#define N_EDGES 320000
#define E_TOT   (N_EDGES + N_NODES)   // 340000
#define HEADS   16

typedef __bf16 bf16;
typedef __attribute__((ext_vector_type(8))) __bf16 bf16x8;
typedef __attribute__((ext_vector_type(4))) __bf16 bf16x4;
typedef __attribute__((ext_vector_type(4))) float  f32x4;

__device__ __forceinline__ void gll16(const void* g, void* l) {
    __builtin_amdgcn_global_load_lds(
        (const __attribute__((address_space(1))) unsigned int*)g,
        (__attribute__((address_space(3))) unsigned int*)l, 16, 0, 0);
}

// ---------------------------------------------------------------------------
// Layer 1: x[N,3] @ W[3,1024] -> hgat bf16, fused alpha_s/alpha_d.
__global__ __launch_bounds__(256)
void k_lin1(const float* __restrict__ x, const float* __restrict__ W,
            const float* __restrict__ aS, const float* __restrict__ aD,
            bf16* __restrict__ hg, float* __restrict__ as_,
            float* __restrict__ ad_) {
    int n = blockIdx.x;
    int t = threadIdx.x;
    int f0 = t * 4, hd = t >> 4;
    float x0 = x[n*3+0], x1 = x[n*3+1], x2 = x[n*3+2];
    float v[4];
    bf16x4 hv;
#pragma unroll
    for (int c = 0; c < 4; ++c) {
        int f = f0 + c;
        v[c] = x0*W[f] + x1*W[1024+f] + x2*W[2048+f];
        hv[c] = (bf16)v[c];
    }
    *reinterpret_cast<bf16x4*>(&hg[(size_t)n * 1024 + f0]) = hv;
    float ps = 0.f, pd = 0.f;
    int cb = (t & 15) * 4;
#pragma unroll
    for (int c = 0; c < 4; ++c) {
        ps = fmaf(v[c], aS[hd*64 + cb + c], ps);
        pd = fmaf(v[c], aD[hd*64 + cb + c], pd);
    }
#pragma unroll
    for (int off = 1; off < 16; off <<= 1) {
        ps += __shfl_xor(ps, off);
        pd += __shfl_xor(pd, off);
    }
    if ((t & 15) == 0) {
        as_[n*16 + hd] = ps;
        ad_[n*16 + hd] = pd;
    }
}

// ---------------------------------------------------------------------------
// W [1024][M] fp32 -> Wt_hi/Wt_lo [M][1024] bf16 (transpose + hi/lo split)
__global__ __launch_bounds__(256)
void k_convW(const float* __restrict__ W, bf16* __restrict__ Th,
             bf16* __restrict__ Tl, int M) {
    __shared__ float t[32][33];
    int m0 = blockIdx.x * 32, k0 = blockIdx.y * 32;
    int j = threadIdx.x & 31, i0 = threadIdx.x >> 5;
#pragma unroll
    for (int s = 0; s < 4; ++s) {
        int i = i0 + s * 8;
        t[i][j] = W[(size_t)(k0 + i) * M + m0 + j];
    }
    __syncthreads();
#pragma unroll
    for (int s = 0; s < 4; ++s) {
        int i = i0 + s * 8;
        float v = t[j][i];
        bf16 hi = (bf16)v;
        bf16 lo = (bf16)(v - (float)hi);
        Th[(size_t)(m0 + i) * 1024 + k0 + j] = hi;
        Tl[(size_t)(m0 + i) * 1024 + k0 + j] = lo;
    }
}

// ---------------------------------------------------------------------------
// 2-pass MFMA GEMM: C = A_bf16 * (Bh+Bl).  blockIdx.x = COL block.
// FUSE: alpha epilogue (C=64 layers), no fp32 C write.
template<bool FUSE>
__global__ __launch_bounds__(256, 2)
void k_gemm3(const bf16* __restrict__ Ah,
             const bf16* __restrict__ Bh, const bf16* __restrict__ Bl,
             float* __restrict__ Cf, bf16* __restrict__ Ch,
             const float* __restrict__ aS, const float* __restrict__ aD,
             float* __restrict__ as_, float* __restrict__ ad_,
             int N, int M) {
    __shared__ __align__(16) bf16 sAh[128 * 32];
    __shared__ __align__(16) bf16 sBh[128 * 32];
    __shared__ __align__(16) bf16 sBl[128 * 32];

    const int tid  = threadIdx.x;
    const int wid  = tid >> 6, lane = tid & 63;
    const int wr   = wid >> 1, wc = wid & 1;
    const int col0 = blockIdx.x * 128, row0 = blockIdx.y * 128;

    f32x4 acc[4][4] = {};

    const int rl = lane >> 2;
    const int gg = lane & 3;
    const int rb0 = wid * 32;
    const int lrow = lane & 15, g4 = lane >> 4;

    for (int k0 = 0; k0 < 1024; k0 += 32) {
#pragma unroll
        for (int half = 0; half < 2; ++half) {
            int rt = rb0 + half * 16 + rl;
            int kc = (gg ^ ((rt >> 1) & 3)) * 8;
            size_t lbase = (size_t)(rb0 + half * 16) * 32;
            int ar = row0 + rt; if (ar >= N) ar = N - 1;
            gll16(Ah + (size_t)ar * 1024 + k0 + kc, sAh + lbase);
            int br = col0 + rt;
            gll16(Bh + (size_t)br * 1024 + k0 + kc, sBh + lbase);
            gll16(Bl + (size_t)br * 1024 + k0 + kc, sBl + lbase);
        }
        __syncthreads();

        bf16x8 ah[4], bh[4], bl[4];
#pragma unroll
        for (int m = 0; m < 4; ++m) {
            int r = wr * 64 + m * 16 + lrow;
            int off = r * 32 + ((g4 ^ ((r >> 1) & 3)) * 8);
            ah[m] = *(const bf16x8*)&sAh[off];
        }
#pragma unroll
        for (int n = 0; n < 4; ++n) {
            int r = wc * 64 + n * 16 + lrow;
            int off = r * 32 + ((g4 ^ ((r >> 1) & 3)) * 8);
            bh[n] = *(const bf16x8*)&sBh[off];
            bl[n] = *(const bf16x8*)&sBl[off];
        }
#pragma unroll
        for (int m = 0; m < 4; ++m)
#pragma unroll
            for (int n = 0; n < 4; ++n) {
                acc[m][n] = __builtin_amdgcn_mfma_f32_16x16x32_bf16(ah[m], bh[n], acc[m][n], 0, 0, 0);
                acc[m][n] = __builtin_amdgcn_mfma_f32_16x16x32_bf16(ah[m], bl[n], acc[m][n], 0, 0, 0);
            }
        __syncthreads();
    }

    // C/D layout: col=lane&15 (lrow), row=(lane>>4)*4+q (g4,q)
#pragma unroll
    for (int m = 0; m < 4; ++m) {
#pragma unroll
        for (int n = 0; n < 4; ++n) {
            int col = col0 + wc * 64 + n * 16 + lrow;
#pragma unroll
            for (int q = 0; q < 4; ++q) {
                int row = row0 + wr * 64 + m * 16 + g4 * 4 + q;
                if (row < N) {
                    float v = acc[m][n][q];
                    if (!FUSE) Cf[(size_t)row * M + col] = v;
                    Ch[(size_t)row * M + col] = (bf16)v;
                }
            }
        }
    }

    if (FUSE) {
        const int hd = blockIdx.x * 2 + wc;
        float asv[4], adv[4];
#pragma unroll
        for (int n = 0; n < 4; ++n) {
            asv[n] = aS[hd * 64 + n * 16 + lrow];
            adv[n] = aD[hd * 64 + n * 16 + lrow];
        }
        float ps[4][4], pd[4][4];
#pragma unroll
        for (int m = 0; m < 4; ++m)
#pragma unroll
            for (int q = 0; q < 4; ++q) {
                float s = 0.f, d = 0.f;
#pragma unroll
                for (int n = 0; n < 4; ++n) {
                    s = fmaf(acc[m][n][q], asv[n], s);
                    d = fmaf(acc[m][n][q], adv[n], d);
                }
                ps[m][q] = s; pd[m][q] = d;
            }
#pragma unroll
        for (int off = 1; off < 16; off <<= 1) {
#pragma unroll
            for (int m = 0; m < 4; ++m)
#pragma unroll
                for (int q = 0; q < 4; ++q) {
                    ps[m][q] += __shfl_xor(ps[m][q], off);
                    pd[m][q] += __shfl_xor(pd[m][q], off);
                }
        }
        if (lrow == 0) {
#pragma unroll
            for (int m = 0; m < 4; ++m)
#pragma unroll
                for (int q = 0; q < 4; ++q) {
                    int row = row0 + wr * 64 + m * 16 + g4 * 4 + q;
                    if (row < N) {
                        as_[row * 16 + hd] = ps[m][q];
                        ad_[row * 16 + hd] = pd[m][q];
                    }
                }
        }
    }
}

// ---------------------------------------------------------------------------
// alpha for layer 6 only (C=48): one wave per (node, head)
__global__ __launch_bounds__(256)
void k_alpha(const float* __restrict__ h, const float* __restrict__ a_s,
             const float* __restrict__ a_d, float* __restrict__ as_out,
             float* __restrict__ ad_out, int C, int M) {
    int pair = blockIdx.x * 4 + (threadIdx.x >> 6);
    int lane = threadIdx.x & 63;
    if (pair >= N_NODES * HEADS) return;
    int n = pair >> 4, hd = pair & 15;
    float vs = 0.f, vd = 0.f;
    if (lane < C) {
        float hv = h[(size_t)n * M + hd * C + lane];
        vs = hv * a_s[hd * C + lane];
        vd = hv * a_d[hd * C + lane];
    }
#pragma unroll
    for (int off = 32; off > 0; off >>= 1) {
        vs += __shfl_down(vs, off);
        vd += __shfl_down(vd, off);
    }
    if (lane == 0) { as_out[pair] = vs; ad_out[pair] = vd; }
}

// ---------------------------------------------------------------------------
// CSR build
__global__ void k_zero_i(int* __restrict__ p, int n) {
    int t = blockIdx.x * 256 + threadIdx.x;
    if (t < n) p[t] = 0;
}
__global__ void k_hist(const int* __restrict__ ei, int* __restrict__ deg) {
    int e = blockIdx.x * 256 + threadIdx.x;
    if (e >= E_TOT) return;
    int d = (e < N_EDGES) ? ei[N_EDGES + e] : e - N_EDGES;
    atomicAdd(&deg[d], 1);
}
__global__ __launch_bounds__(256)
void k_scan(const int* __restrict__ deg, int* __restrict__ rowstart,
            int* __restrict__ cursor) {
    __shared__ int sh[256];
    int carry = 0;
    for (int base = 0; base < N_NODES; base += 256) {
        int i = base + threadIdx.x;
        int v = (i < N_NODES) ? deg[i] : 0;
        sh[threadIdx.x] = v;
        __syncthreads();
        for (int off = 1; off < 256; off <<= 1) {
            int t = (threadIdx.x >= off) ? sh[threadIdx.x - off] : 0;
            __syncthreads();
            sh[threadIdx.x] += t;
            __syncthreads();
        }
        if (i < N_NODES) {
            int excl = carry + sh[threadIdx.x] - v;
            rowstart[i] = excl;
            cursor[i] = excl;
        }
        carry += sh[255];
        __syncthreads();
    }
    if (threadIdx.x == 0) rowstart[N_NODES] = carry;
}
__global__ void k_scatter(const int* __restrict__ ei, int* __restrict__ cursor,
                          int* __restrict__ csr_src) {
    int e = blockIdx.x * 256 + threadIdx.x;
    if (e >= E_TOT) return;
    int s, d;
    if (e < N_EDGES) { s = ei[e]; d = ei[N_EDGES + e]; }
    else             { s = d = e - N_EDGES; }
    int slot = atomicAdd(&cursor[d], 1);
    csr_src[slot] = s;
}

// ---------------------------------------------------------------------------
// aggregation M=1024, online softmax fused; bf16 out only.
__global__ __launch_bounds__(256)
void k_agg1024(const bf16* __restrict__ hg, const int* __restrict__ rowstart,
               const int* __restrict__ csr_src, const float* __restrict__ as_,
               const float* __restrict__ ad_, const float* __restrict__ bias,
               bf16* __restrict__ oh) {
    int n = blockIdx.x * 2 + (threadIdx.x >> 7);
    int tloc = threadIdx.x & 127;
    int f0 = tloc * 8;
    int hd = tloc >> 3;
    int s0 = rowstart[n], s1 = rowstart[n + 1];
    float adv = ad_[n * 16 + hd];
    float m = -1e30f, den = 0.f;
    float acc[8] = {};
    for (int j = s0; j < s1; ++j) {
        int s = csr_src[j];
        float v = as_[s * 16 + hd] + adv;
        v = v > 0.f ? v : 0.2f * v;
        bf16x8 hv = *reinterpret_cast<const bf16x8*>(&hg[(size_t)s * 1024 + f0]);
        float nm = fmaxf(m, v);
        float rm = __expf(m - nm);
        float re = __expf(v - nm);
        den = den * rm + re;
#pragma unroll
        for (int c = 0; c < 8; ++c)
            acc[c] = fmaf(acc[c], rm, re * (float)hv[c]);
        m = nm;
    }
    float inv = 1.f / (den + 1e-16f);
    bf16x8 vh;
#pragma unroll
    for (int c = 0; c < 8; ++c) {
        float r = fmaxf(fmaf(acc[c], inv, bias[f0 + c]), 0.f);
        vh[c] = (bf16)r;
    }
    *reinterpret_cast<bf16x8*>(&oh[(size_t)n * 1024 + f0]) = vh;
}

// last layer M=768 (C=48): online softmax, fp32 out, no relu
__global__ __launch_bounds__(256)
void k_agg768(const bf16* __restrict__ hg, const int* __restrict__ rowstart,
              const int* __restrict__ csr_src, const float* __restrict__ as_,
              const float* __restrict__ ad_, const float* __restrict__ bias,
              float* __restrict__ out) {
    int n = blockIdx.x * 2 + (threadIdx.x >> 7);
    int tloc = threadIdx.x & 127;
    if (tloc >= 96) return;
    int f0 = tloc * 8;
    int hd = f0 / 48;
    int s0 = rowstart[n], s1 = rowstart[n + 1];
    float adv = ad_[n * 16 + hd];
    float m = -1e30f, den = 0.f;
    float acc[8] = {};
    for (int j = s0; j < s1; ++j) {
        int s = csr_src[j];
        float v = as_[s * 16 + hd] + adv;
        v = v > 0.f ? v : 0.2f * v;
        bf16x8 hv = *reinterpret_cast<const bf16x8*>(&hg[(size_t)s * 768 + f0]);
        float nm = fmaxf(m, v);
        float rm = __expf(m - nm);
        float re = __expf(v - nm);
        den = den * rm + re;
#pragma unroll
        for (int c = 0; c < 8; ++c)
            acc[c] = fmaf(acc[c], rm, re * (float)hv[c]);
        m = nm;
    }
    float inv = 1.f / (den + 1e-16f);
#pragma unroll
    for (int c = 0; c < 8; ++c)
        out[(size_t)n * 768 + f0 + c] = fmaf(acc[c], inv, bias[f0 + c]);
}

// ---------------------------------------------------------------------------
// final: out[1,768] = sum_n x[n, :]
__global__ __launch_bounds__(256)
void k_colsum(const float* __restrict__ x, float* __restrict__ out) {
    int f = blockIdx.x * 256 + threadIdx.x;
    int chunk = blockIdx.y;
    int n0 = chunk * 625, n1 = n0 + 625;
    float s = 0.f;
    for (int n = n0; n < n1; ++n) s += x[(size_t)n * 768 + f];
    atomicAdd(&out[f], s);
}

// ---------------------------------------------------------------------------
extern "C" void kernel_launch(void* const* d_in, const int* in_sizes, int n_in,
                              void* d_out, int out_size, void* d_ws, size_t ws_size,
                              hipStream_t stream) {
    const float* x0 = (const float*)d_in[0];
    const int*   ei = (const int*)d_in[1];

    char* w = (char*)d_ws;
    float* xB  = (float*)w;                       // layer-6 fp32 C [N,1024 alloc]
    float* xOut = (float*)w;                      // alias: layer-6 agg out [N,768] fp32
    w += (size_t)N_NODES * 1024 * sizeof(float);  // 80 MB region covers both uses
    bf16*  hgat = (bf16*)w; w += (size_t)N_NODES * 1024 * sizeof(bf16);
    bf16*  x_hi = (bf16*)w; w += (size_t)N_NODES * 1024 * sizeof(bf16);
    float* as_  = (float*)w; w += (size_t)N_NODES * HEADS * sizeof(float);
    float* ad_  = (float*)w; w += (size_t)N_NODES * HEADS * sizeof(float);
    bf16* Wt_hi = (bf16*)w; w += (size_t)1024 * 1024 * sizeof(bf16);
    bf16* Wt_lo = (bf16*)w; w += (size_t)1024 * 1024 * sizeof(bf16);
    int* deg      = (int*)w; w += N_NODES * sizeof(int);
    int* rowstart = (int*)w; w += (N_NODES + 1) * sizeof(int);
    int* cursor   = (int*)w; w += N_NODES * sizeof(int);
    int* csr_src  = (int*)w; w += E_TOT * sizeof(int);

    // ---- CSR build (once) ----
    k_zero_i<<<(N_NODES + 255) / 256, 256, 0, stream>>>(deg, N_NODES);
    k_hist<<<(E_TOT + 255) / 256, 256, 0, stream>>>(ei, deg);
    k_scan<<<1, 256, 0, stream>>>(deg, rowstart, cursor);
    k_scatter<<<(E_TOT + 255) / 256, 256, 0, stream>>>(ei, cursor, csr_src);

    for (int l = 0; l < 6; ++l) {
        const float* W  = (const float*)d_in[2 + 4 * l + 0];
        const float* aS = (const float*)d_in[2 + 4 * l + 1];
        const float* aD = (const float*)d_in[2 + 4 * l + 2];
        const float* bv = (const float*)d_in[2 + 4 * l + 3];
        int M = (l == 5) ? 768 : 1024;

        if (l == 0) {
            k_lin1<<<N_NODES, 256, 0, stream>>>(x0, W, aS, aD, hgat, as_, ad_);
        } else {
            dim3 tg(M / 32, 32);
            k_convW<<<tg, 256, 0, stream>>>(W, Wt_hi, Wt_lo, M);
            dim3 grid(M / 128, (N_NODES + 127) / 128);   // x = COL block
            if (l < 5) {
                k_gemm3<true><<<grid, 256, 0, stream>>>(
                    x_hi, Wt_hi, Wt_lo, nullptr, hgat, aS, aD, as_, ad_,
                    N_NODES, M);
            } else {
                k_gemm3<false><<<grid, 256, 0, stream>>>(
                    x_hi, Wt_hi, Wt_lo, xB, hgat, nullptr, nullptr,
                    nullptr, nullptr, N_NODES, M);
                k_alpha<<<(N_NODES * HEADS + 3) / 4, 256, 0, stream>>>(
                    xB, aS, aD, as_, ad_, 48, 768);
            }
        }
        if (l < 5) {
            k_agg1024<<<N_NODES / 2, 256, 0, stream>>>(
                hgat, rowstart, csr_src, as_, ad_, bv, x_hi);
        } else {
            k_agg768<<<N_NODES / 2, 256, 0, stream>>>(
                hgat, rowstart, csr_src, as_, ad_, bv, xOut);
        }
    }

    hipMemsetAsync(d_out, 0, (size_t)out_size * sizeof(float), stream);
    dim3 cgrid(3, 32);
    k_colsum<<<cgrid, 256, 0, stream>>>(xOut, (float*)d_out);
}

// Round 7
// 1217.845 us; speedup vs baseline: 3.4304x; 1.0809x over previous
//
#include <hip/hip_runtime.h>
#include <cstddef>
#include <cstdint>

#define N_NODES 20000
#define N_EDGES 320000
#define E_TOT   (N_EDGES + N_NODES)   // 340000
#define HEADS   16

typedef __bf16 bf16;
typedef __attribute__((ext_vector_type(8))) __bf16 bf16x8;
typedef __attribute__((ext_vector_type(4))) __bf16 bf16x4;
typedef __attribute__((ext_vector_type(4))) float  f32x4;

__device__ __forceinline__ void gll16(const void* g, void* l) {
    __builtin_amdgcn_global_load_lds(
        (const __attribute__((address_space(1))) unsigned int*)g,
        (__attribute__((address_space(3))) unsigned int*)l, 16, 0, 0);
}

// ---------------------------------------------------------------------------
// Layer 1: x[N,3] @ W[3,1024] -> hgat bf16, fused alpha_s/alpha_d.
__global__ __launch_bounds__(256)
void k_lin1(const float* __restrict__ x, const float* __restrict__ W,
            const float* __restrict__ aS, const float* __restrict__ aD,
            bf16* __restrict__ hg, float* __restrict__ as_,
            float* __restrict__ ad_) {
    int n = blockIdx.x;
    int t = threadIdx.x;
    int f0 = t * 4, hd = t >> 4;
    float x0 = x[n*3+0], x1 = x[n*3+1], x2 = x[n*3+2];
    float v[4];
    bf16x4 hv;
#pragma unroll
    for (int c = 0; c < 4; ++c) {
        int f = f0 + c;
        v[c] = x0*W[f] + x1*W[1024+f] + x2*W[2048+f];
        hv[c] = (bf16)v[c];
    }
    *reinterpret_cast<bf16x4*>(&hg[(size_t)n * 1024 + f0]) = hv;
    float ps = 0.f, pd = 0.f;
    int cb = (t & 15) * 4;
#pragma unroll
    for (int c = 0; c < 4; ++c) {
        ps = fmaf(v[c], aS[hd*64 + cb + c], ps);
        pd = fmaf(v[c], aD[hd*64 + cb + c], pd);
    }
#pragma unroll
    for (int off = 1; off < 16; off <<= 1) {
        ps += __shfl_xor(ps, off);
        pd += __shfl_xor(pd, off);
    }
    if ((t & 15) == 0) {
        as_[n*16 + hd] = ps;
        ad_[n*16 + hd] = pd;
    }
}

// ---------------------------------------------------------------------------
// W [1024][M] fp32 -> Wt_hi (+ optional Wt_lo) [M][1024] bf16
__global__ __launch_bounds__(256)
void k_convW(const float* __restrict__ W, bf16* __restrict__ Th,
             bf16* __restrict__ Tl, int M) {
    __shared__ float t[32][33];
    int m0 = blockIdx.x * 32, k0 = blockIdx.y * 32;
    int j = threadIdx.x & 31, i0 = threadIdx.x >> 5;
#pragma unroll
    for (int s = 0; s < 4; ++s) {
        int i = i0 + s * 8;
        t[i][j] = W[(size_t)(k0 + i) * M + m0 + j];
    }
    __syncthreads();
#pragma unroll
    for (int s = 0; s < 4; ++s) {
        int i = i0 + s * 8;
        float v = t[j][i];
        bf16 hi = (bf16)v;
        Th[(size_t)(m0 + i) * 1024 + k0 + j] = hi;
        if (Tl) Tl[(size_t)(m0 + i) * 1024 + k0 + j] = (bf16)(v - (float)hi);
    }
}

// ---------------------------------------------------------------------------
// MFMA GEMM: C = A_bf16 * (Bh [+ Bl]).  blockIdx.x = COL block (XCD-pinned B).
// FUSE: alpha epilogue (C=64 layers), no fp32 C write.  TWOB: B hi+lo 2-pass.
template<bool FUSE, bool TWOB>
__global__ __launch_bounds__(256, 2)
void k_gemm3(const bf16* __restrict__ Ah,
             const bf16* __restrict__ Bh, const bf16* __restrict__ Bl,
             float* __restrict__ Cf, bf16* __restrict__ Ch,
             const float* __restrict__ aS, const float* __restrict__ aD,
             float* __restrict__ as_, float* __restrict__ ad_,
             int N, int M) {
    __shared__ __align__(16) bf16 sAh[128 * 32];
    __shared__ __align__(16) bf16 sBh[128 * 32];
    __shared__ __align__(16) bf16 sBl[TWOB ? 128 * 32 : 8];

    const int tid  = threadIdx.x;
    const int wid  = tid >> 6, lane = tid & 63;
    const int wr   = wid >> 1, wc = wid & 1;
    const int col0 = blockIdx.x * 128, row0 = blockIdx.y * 128;

    f32x4 acc[4][4] = {};

    const int rl = lane >> 2;
    const int gg = lane & 3;
    const int rb0 = wid * 32;
    const int lrow = lane & 15, g4 = lane >> 4;

    for (int k0 = 0; k0 < 1024; k0 += 32) {
#pragma unroll
        for (int half = 0; half < 2; ++half) {
            int rt = rb0 + half * 16 + rl;
            int kc = (gg ^ ((rt >> 1) & 3)) * 8;
            size_t lbase = (size_t)(rb0 + half * 16) * 32;
            int ar = row0 + rt; if (ar >= N) ar = N - 1;
            gll16(Ah + (size_t)ar * 1024 + k0 + kc, sAh + lbase);
            int br = col0 + rt;
            gll16(Bh + (size_t)br * 1024 + k0 + kc, sBh + lbase);
            if (TWOB) gll16(Bl + (size_t)br * 1024 + k0 + kc, sBl + lbase);
        }
        __syncthreads();

        bf16x8 ah[4], bh[4], bl[4];
#pragma unroll
        for (int m = 0; m < 4; ++m) {
            int r = wr * 64 + m * 16 + lrow;
            int off = r * 32 + ((g4 ^ ((r >> 1) & 3)) * 8);
            ah[m] = *(const bf16x8*)&sAh[off];
        }
#pragma unroll
        for (int n = 0; n < 4; ++n) {
            int r = wc * 64 + n * 16 + lrow;
            int off = r * 32 + ((g4 ^ ((r >> 1) & 3)) * 8);
            bh[n] = *(const bf16x8*)&sBh[off];
            if (TWOB) bl[n] = *(const bf16x8*)&sBl[off];
        }
#pragma unroll
        for (int m = 0; m < 4; ++m)
#pragma unroll
            for (int n = 0; n < 4; ++n) {
                acc[m][n] = __builtin_amdgcn_mfma_f32_16x16x32_bf16(ah[m], bh[n], acc[m][n], 0, 0, 0);
                if (TWOB)
                    acc[m][n] = __builtin_amdgcn_mfma_f32_16x16x32_bf16(ah[m], bl[n], acc[m][n], 0, 0, 0);
            }
        __syncthreads();
    }

    // C/D layout: col=lane&15 (lrow), row=(lane>>4)*4+q (g4,q)
#pragma unroll
    for (int m = 0; m < 4; ++m) {
#pragma unroll
        for (int n = 0; n < 4; ++n) {
            int col = col0 + wc * 64 + n * 16 + lrow;
#pragma unroll
            for (int q = 0; q < 4; ++q) {
                int row = row0 + wr * 64 + m * 16 + g4 * 4 + q;
                if (row < N) {
                    float v = acc[m][n][q];
                    if (!FUSE) Cf[(size_t)row * M + col] = v;
                    Ch[(size_t)row * M + col] = (bf16)v;
                }
            }
        }
    }

    if (FUSE) {
        const int hd = blockIdx.x * 2 + wc;
        float asv[4], adv[4];
#pragma unroll
        for (int n = 0; n < 4; ++n) {
            asv[n] = aS[hd * 64 + n * 16 + lrow];
            adv[n] = aD[hd * 64 + n * 16 + lrow];
        }
        float ps[4][4], pd[4][4];
#pragma unroll
        for (int m = 0; m < 4; ++m)
#pragma unroll
            for (int q = 0; q < 4; ++q) {
                float s = 0.f, d = 0.f;
#pragma unroll
                for (int n = 0; n < 4; ++n) {
                    s = fmaf(acc[m][n][q], asv[n], s);
                    d = fmaf(acc[m][n][q], adv[n], d);
                }
                ps[m][q] = s; pd[m][q] = d;
            }
#pragma unroll
        for (int off = 1; off < 16; off <<= 1) {
#pragma unroll
            for (int m = 0; m < 4; ++m)
#pragma unroll
                for (int q = 0; q < 4; ++q) {
                    ps[m][q] += __shfl_xor(ps[m][q], off);
                    pd[m][q] += __shfl_xor(pd[m][q], off);
                }
        }
        if (lrow == 0) {
#pragma unroll
            for (int m = 0; m < 4; ++m)
#pragma unroll
                for (int q = 0; q < 4; ++q) {
                    int row = row0 + wr * 64 + m * 16 + g4 * 4 + q;
                    if (row < N) {
                        as_[row * 16 + hd] = ps[m][q];
                        ad_[row * 16 + hd] = pd[m][q];
                    }
                }
        }
    }
}

// ---------------------------------------------------------------------------
// alpha for layer 6 only (C=48): one wave per (node, head)
__global__ __launch_bounds__(256)
void k_alpha(const float* __restrict__ h, const float* __restrict__ a_s,
             const float* __restrict__ a_d, float* __restrict__ as_out,
             float* __restrict__ ad_out, int C, int M) {
    int pair = blockIdx.x * 4 + (threadIdx.x >> 6);
    int lane = threadIdx.x & 63;
    if (pair >= N_NODES * HEADS) return;
    int n = pair >> 4, hd = pair & 15;
    float vs = 0.f, vd = 0.f;
    if (lane < C) {
        float hv = h[(size_t)n * M + hd * C + lane];
        vs = hv * a_s[hd * C + lane];
        vd = hv * a_d[hd * C + lane];
    }
#pragma unroll
    for (int off = 32; off > 0; off >>= 1) {
        vs += __shfl_down(vs, off);
        vd += __shfl_down(vd, off);
    }
    if (lane == 0) { as_out[pair] = vs; ad_out[pair] = vd; }
}

// ---------------------------------------------------------------------------
// CSR build
__global__ void k_zero_i(int* __restrict__ p, int n) {
    int t = blockIdx.x * 256 + threadIdx.x;
    if (t < n) p[t] = 0;
}
__global__ void k_hist(const int* __restrict__ ei, int* __restrict__ deg) {
    int e = blockIdx.x * 256 + threadIdx.x;
    if (e >= E_TOT) return;
    int d = (e < N_EDGES) ? ei[N_EDGES + e] : e - N_EDGES;
    atomicAdd(&deg[d], 1);
}
__global__ __launch_bounds__(256)
void k_scan(const int* __restrict__ deg, int* __restrict__ rowstart,
            int* __restrict__ cursor) {
    __shared__ int sh[256];
    int carry = 0;
    for (int base = 0; base < N_NODES; base += 256) {
        int i = base + threadIdx.x;
        int v = (i < N_NODES) ? deg[i] : 0;
        sh[threadIdx.x] = v;
        __syncthreads();
        for (int off = 1; off < 256; off <<= 1) {
            int t = (threadIdx.x >= off) ? sh[threadIdx.x - off] : 0;
            __syncthreads();
            sh[threadIdx.x] += t;
            __syncthreads();
        }
        if (i < N_NODES) {
            int excl = carry + sh[threadIdx.x] - v;
            rowstart[i] = excl;
            cursor[i] = excl;
        }
        carry += sh[255];
        __syncthreads();
    }
    if (threadIdx.x == 0) rowstart[N_NODES] = carry;
}
__global__ void k_scatter(const int* __restrict__ ei, int* __restrict__ cursor,
                          int* __restrict__ csr_src) {
    int e = blockIdx.x * 256 + threadIdx.x;
    if (e >= E_TOT) return;
    int s, d;
    if (e < N_EDGES) { s = ei[e]; d = ei[N_EDGES + e]; }
    else             { s = d = e - N_EDGES; }
    int slot = atomicAdd(&cursor[d], 1);
    csr_src[slot] = s;
}

// ---------------------------------------------------------------------------
// aggregation M=1024, online softmax fused; f-sliced across XCDs.
// grid (8, 1250): blockIdx.x = 128-col slice (== XCD via round-robin),
// block = 16 nodes x 16 threads, 8 cols/thread.
__global__ __launch_bounds__(256)
void k_agg1024(const bf16* __restrict__ hg, const int* __restrict__ rowstart,
               const int* __restrict__ csr_src, const float* __restrict__ as_,
               const float* __restrict__ ad_, const float* __restrict__ bias,
               bf16* __restrict__ oh) {
    int slice = blockIdx.x;
    int n = blockIdx.y * 16 + (threadIdx.x >> 4);
    int sub = threadIdx.x & 15;
    int f0 = slice * 128 + sub * 8;
    int hd = f0 >> 6;
    int s0 = rowstart[n], s1 = rowstart[n + 1];
    float adv = ad_[n * 16 + hd];
    float m = -1e30f, den = 0.f;
    float acc[8] = {};
    for (int j = s0; j < s1; ++j) {
        int s = csr_src[j];
        float v = as_[s * 16 + hd] + adv;
        v = v > 0.f ? v : 0.2f * v;
        bf16x8 hv = *reinterpret_cast<const bf16x8*>(&hg[(size_t)s * 1024 + f0]);
        float nm = fmaxf(m, v);
        float rm = __expf(m - nm);
        float re = __expf(v - nm);
        den = den * rm + re;
#pragma unroll
        for (int c = 0; c < 8; ++c)
            acc[c] = fmaf(acc[c], rm, re * (float)hv[c]);
        m = nm;
    }
    float inv = 1.f / (den + 1e-16f);
    bf16x8 vh;
#pragma unroll
    for (int c = 0; c < 8; ++c) {
        float r = fmaxf(fmaf(acc[c], inv, bias[f0 + c]), 0.f);
        vh[c] = (bf16)r;
    }
    *reinterpret_cast<bf16x8*>(&oh[(size_t)n * 1024 + f0]) = vh;
}

// last layer M=768 (C=48): online softmax, fp32 out, no relu
__global__ __launch_bounds__(256)
void k_agg768(const bf16* __restrict__ hg, const int* __restrict__ rowstart,
              const int* __restrict__ csr_src, const float* __restrict__ as_,
              const float* __restrict__ ad_, const float* __restrict__ bias,
              float* __restrict__ out) {
    int n = blockIdx.x * 2 + (threadIdx.x >> 7);
    int tloc = threadIdx.x & 127;
    if (tloc >= 96) return;
    int f0 = tloc * 8;
    int hd = f0 / 48;
    int s0 = rowstart[n], s1 = rowstart[n + 1];
    float adv = ad_[n * 16 + hd];
    float m = -1e30f, den = 0.f;
    float acc[8] = {};
    for (int j = s0; j < s1; ++j) {
        int s = csr_src[j];
        float v = as_[s * 16 + hd] + adv;
        v = v > 0.f ? v : 0.2f * v;
        bf16x8 hv = *reinterpret_cast<const bf16x8*>(&hg[(size_t)s * 768 + f0]);
        float nm = fmaxf(m, v);
        float rm = __expf(m - nm);
        float re = __expf(v - nm);
        den = den * rm + re;
#pragma unroll
        for (int c = 0; c < 8; ++c)
            acc[c] = fmaf(acc[c], rm, re * (float)hv[c]);
        m = nm;
    }
    float inv = 1.f / (den + 1e-16f);
#pragma unroll
    for (int c = 0; c < 8; ++c)
        out[(size_t)n * 768 + f0 + c] = fmaf(acc[c], inv, bias[f0 + c]);
}

// ---------------------------------------------------------------------------
// final: out[1,768] = sum_n x[n, :]
__global__ __launch_bounds__(256)
void k_colsum(const float* __restrict__ x, float* __restrict__ out) {
    int f = blockIdx.x * 256 + threadIdx.x;
    int chunk = blockIdx.y;
    int n0 = chunk * 625, n1 = n0 + 625;
    float s = 0.f;
    for (int n = n0; n < n1; ++n) s += x[(size_t)n * 768 + f];
    atomicAdd(&out[f], s);
}

// ---------------------------------------------------------------------------
extern "C" void kernel_launch(void* const* d_in, const int* in_sizes, int n_in,
                              void* d_out, int out_size, void* d_ws, size_t ws_size,
                              hipStream_t stream) {
    const float* x0 = (const float*)d_in[0];
    const int*   ei = (const int*)d_in[1];

    char* w = (char*)d_ws;
    float* xB  = (float*)w;                       // layer-6 fp32 C [N,1024 alloc]
    float* xOut = (float*)w;                      // alias: layer-6 agg out [N,768] fp32
    w += (size_t)N_NODES * 1024 * sizeof(float);  // 80 MB region covers both uses
    bf16*  hgat = (bf16*)w; w += (size_t)N_NODES * 1024 * sizeof(bf16);
    bf16*  x_hi = (bf16*)w; w += (size_t)N_NODES * 1024 * sizeof(bf16);
    float* as_  = (float*)w; w += (size_t)N_NODES * HEADS * sizeof(float);
    float* ad_  = (float*)w; w += (size_t)N_NODES * HEADS * sizeof(float);
    bf16* Wt_hi = (bf16*)w; w += (size_t)1024 * 1024 * sizeof(bf16);
    bf16* Wt_lo = (bf16*)w; w += (size_t)1024 * 1024 * sizeof(bf16);
    int* deg      = (int*)w; w += N_NODES * sizeof(int);
    int* rowstart = (int*)w; w += (N_NODES + 1) * sizeof(int);
    int* cursor   = (int*)w; w += N_NODES * sizeof(int);
    int* csr_src  = (int*)w; w += E_TOT * sizeof(int);

    // ---- CSR build (once) ----
    k_zero_i<<<(N_NODES + 255) / 256, 256, 0, stream>>>(deg, N_NODES);
    k_hist<<<(E_TOT + 255) / 256, 256, 0, stream>>>(ei, deg);
    k_scan<<<1, 256, 0, stream>>>(deg, rowstart, cursor);
    k_scatter<<<(E_TOT + 255) / 256, 256, 0, stream>>>(ei, cursor, csr_src);

    for (int l = 0; l < 6; ++l) {
        const float* W  = (const float*)d_in[2 + 4 * l + 0];
        const float* aS = (const float*)d_in[2 + 4 * l + 1];
        const float* aD = (const float*)d_in[2 + 4 * l + 2];
        const float* bv = (const float*)d_in[2 + 4 * l + 3];
        int M = (l == 5) ? 768 : 1024;

        if (l == 0) {
            k_lin1<<<N_NODES, 256, 0, stream>>>(x0, W, aS, aD, hgat, as_, ad_);
        } else {
            dim3 tg(M / 32, 32);
            dim3 grid(M / 128, (N_NODES + 127) / 128);   // x = COL block
            if (l < 5) {
                k_convW<<<tg, 256, 0, stream>>>(W, Wt_hi, nullptr, M);
                k_gemm3<true, false><<<grid, 256, 0, stream>>>(
                    x_hi, Wt_hi, nullptr, nullptr, hgat, aS, aD, as_, ad_,
                    N_NODES, M);
            } else {
                k_convW<<<tg, 256, 0, stream>>>(W, Wt_hi, Wt_lo, M);
                k_gemm3<false, true><<<grid, 256, 0, stream>>>(
                    x_hi, Wt_hi, Wt_lo, xB, hgat, nullptr, nullptr,
                    nullptr, nullptr, N_NODES, M);
                k_alpha<<<(N_NODES * HEADS + 3) / 4, 256, 0, stream>>>(
                    xB, aS, aD, as_, ad_, 48, 768);
            }
        }
        if (l < 5) {
            dim3 agrid(8, N_NODES / 16);
            k_agg1024<<<agrid, 256, 0, stream>>>(
                hgat, rowstart, csr_src, as_, ad_, bv, x_hi);
        } else {
            k_agg768<<<N_NODES / 2, 256, 0, stream>>>(
                hgat, rowstart, csr_src, as_, ad_, bv, xOut);
        }
    }

    hipMemsetAsync(d_out, 0, (size_t)out_size * sizeof(float), stream);
    dim3 cgrid(3, 32);
    k_colsum<<<cgrid, 256, 0, stream>>>(xOut, (float*)d_out);
}